// Round 1
// baseline (595.111 us; speedup 1.0000x reference)
//
#include <hip/hip_runtime.h>
#include <math.h>

#define NN 100000
#define NE 1600000
#define IN_DIM 256
#define HD 128           // HEADS*OUT_DIM
#define NEG_SLOPE 0.2f
#define SCAN_CHUNK 2048
#define NB_SCAN ((NN + SCAN_CHUNK - 1) / SCAN_CHUNK)   // 49

// ---------------- GEMM: feat[N,128] = x[N,256] @ W[256,128] ----------------
__global__ __launch_bounds__(256) void gemm_kernel(const float* __restrict__ x,
                                                   const float* __restrict__ W,
                                                   float* __restrict__ feat) {
    __shared__ float As[16][64];    // A transposed: As[k][row]
    __shared__ float Bs[16][128];
    const int tid = threadIdx.x;
    const int block_row = blockIdx.x * 64;
    const int tx = tid & 31;        // column group (4 cols each)
    const int ty = tid >> 5;        // row group (8 rows each)
    const int arow  = tid >> 2;     // 0..63
    const int acol4 = (tid & 3) << 2;
    const int brow  = tid >> 5;     // 0..7
    const int bcol4 = (tid & 31) << 2;

    float acc[8][4];
#pragma unroll
    for (int r = 0; r < 8; ++r)
#pragma unroll
        for (int c = 0; c < 4; ++c) acc[r][c] = 0.f;

    int grow = block_row + arow;
    if (grow >= NN) grow = NN - 1;              // clamp (stores are guarded)
    const float* xrow = x + (size_t)grow * IN_DIM;

    for (int k0 = 0; k0 < IN_DIM; k0 += 16) {
        float4 av = *(const float4*)(xrow + k0 + acol4);
        As[acol4 + 0][arow] = av.x;
        As[acol4 + 1][arow] = av.y;
        As[acol4 + 2][arow] = av.z;
        As[acol4 + 3][arow] = av.w;
        float4 bv0 = *(const float4*)(W + (size_t)(k0 + brow) * HD + bcol4);
        float4 bv1 = *(const float4*)(W + (size_t)(k0 + brow + 8) * HD + bcol4);
        *(float4*)&Bs[brow][bcol4]     = bv0;
        *(float4*)&Bs[brow + 8][bcol4] = bv1;
        __syncthreads();
#pragma unroll
        for (int kk = 0; kk < 16; ++kk) {
            float4 a0 = *(const float4*)&As[kk][ty * 8];
            float4 a1 = *(const float4*)&As[kk][ty * 8 + 4];
            float4 b  = *(const float4*)&Bs[kk][tx * 4];
            float ar[8] = {a0.x, a0.y, a0.z, a0.w, a1.x, a1.y, a1.z, a1.w};
            float br[4] = {b.x, b.y, b.z, b.w};
#pragma unroll
            for (int r = 0; r < 8; ++r)
#pragma unroll
                for (int c = 0; c < 4; ++c)
                    acc[r][c] = fmaf(ar[r], br[c], acc[r][c]);
        }
        __syncthreads();
    }
#pragma unroll
    for (int r = 0; r < 8; ++r) {
        int row = block_row + ty * 8 + r;
        if (row < NN) {
            float4 o = make_float4(acc[r][0], acc[r][1], acc[r][2], acc[r][3]);
            *(float4*)(feat + (size_t)row * HD + tx * 4) = o;
        }
    }
}

// ---------------- el/er: per-node attention logits ----------------
// one wave per node; lane L holds features 2L,2L+1 of head h=L>>4
__global__ __launch_bounds__(256) void eler_kernel(const float* __restrict__ feat,
                                                   const float* __restrict__ attn_l,
                                                   const float* __restrict__ attn_r,
                                                   float* __restrict__ el,
                                                   float* __restrict__ er) {
    int node = (blockIdx.x * blockDim.x + threadIdx.x) >> 6;
    int lane = threadIdx.x & 63;
    if (node >= NN) return;
    float2 f = *(const float2*)(feat + (size_t)node * HD + lane * 2);
    int h  = lane >> 4;
    int dd = (lane * 2) & 31;
    float pl = f.x * attn_l[h * 32 + dd] + f.y * attn_l[h * 32 + dd + 1];
    float pr = f.x * attn_r[h * 32 + dd] + f.y * attn_r[h * 32 + dd + 1];
#pragma unroll
    for (int o = 1; o < 16; o <<= 1) {
        pl += __shfl_xor(pl, o);
        pr += __shfl_xor(pr, o);
    }
    if ((lane & 15) == 0) {
        el[node * 4 + h] = pl;
        er[node * 4 + h] = pr;
    }
}

// ---------------- degree histogram ----------------
__global__ void hist_kernel(const int* __restrict__ dst, int* __restrict__ deg) {
    int e = blockIdx.x * blockDim.x + threadIdx.x;
    if (e < NE) atomicAdd(&deg[dst[e]], 1);
}

// ---------------- exclusive scan (3 kernels) ----------------
__global__ __launch_bounds__(256) void scan1_kernel(const int* __restrict__ deg,
                                                    int* __restrict__ offs,
                                                    int* __restrict__ bsum) {
    __shared__ int sh[256];
    int b = blockIdx.x, t = threadIdx.x;
    int base = b * SCAN_CHUNK + t * 8;
    int v[8];
    int s = 0;
#pragma unroll
    for (int j = 0; j < 8; ++j) {
        int i = base + j;
        v[j] = (i < NN) ? deg[i] : 0;
        s += v[j];
    }
    sh[t] = s;
    __syncthreads();
    for (int o = 1; o < 256; o <<= 1) {
        int add = (t >= o) ? sh[t - o] : 0;
        __syncthreads();
        sh[t] += add;
        __syncthreads();
    }
    int incl = sh[t];
    int run = incl - s;   // exclusive within block
#pragma unroll
    for (int j = 0; j < 8; ++j) {
        int i = base + j;
        if (i < NN) offs[i] = run;
        run += v[j];
    }
    if (t == 255) bsum[b] = incl;   // block total
}

__global__ void scan2_kernel(int* __restrict__ bsum, int* __restrict__ offs) {
    int t = threadIdx.x;            // 64 threads, one wave
    int x = (t < NB_SCAN) ? bsum[t] : 0;
    int v = x;
#pragma unroll
    for (int o = 1; o < 64; o <<= 1) {
        int u = __shfl_up(v, o);
        if (t >= o) v += u;
    }
    if (t < NB_SCAN) bsum[t] = v - x;       // exclusive block offset
    if (t == NB_SCAN - 1) offs[NN] = v;     // grand total (== NE)
}

__global__ __launch_bounds__(256) void scan3_kernel(int* __restrict__ offs,
                                                    const int* __restrict__ bsum) {
    int b = blockIdx.x;
    int add = bsum[b];
    if (add == 0) return;
    int base = b * SCAN_CHUNK + threadIdx.x * 8;
#pragma unroll
    for (int j = 0; j < 8; ++j) {
        int i = base + j;
        if (i < NN) offs[i] += add;
    }
}

// ---------------- CSR bucket fill ----------------
__global__ void fill_csr_kernel(const int* __restrict__ src, const int* __restrict__ dst,
                                const int* __restrict__ offs, int* __restrict__ cursor,
                                int* __restrict__ csr_src) {
    int e = blockIdx.x * blockDim.x + threadIdx.x;
    if (e >= NE) return;
    int d = dst[e];
    int p = offs[d] + atomicAdd(&cursor[d], 1);
    csr_src[p] = src[e];
}

// ---------------- per-node softmax + aggregation ----------------
// one wave per dst node. lane L: head h=L>>4, features 2L,2L+1 (dd = 2L&31)
__global__ __launch_bounds__(256) void aggregate_kernel(const float* __restrict__ feat,
                                                        const float* __restrict__ el,
                                                        const float* __restrict__ er,
                                                        const int* __restrict__ offs,
                                                        const int* __restrict__ csr_src,
                                                        float* __restrict__ out) {
    int node = (blockIdx.x * blockDim.x + threadIdx.x) >> 6;
    int lane = threadIdx.x & 63;
    if (node >= NN) return;
    int beg = offs[node], end = offs[node + 1];
    int h = lane >> 4;

    if (beg == end) {   // zero in-degree -> zeros
        if (lane < 16) *(float2*)(out + (size_t)node * 32 + lane * 2) = make_float2(0.f, 0.f);
        return;
    }

    float er_h = er[node * 4 + h];
    int sub = lane & 15;

    // pass 1: segment max per head (16 lanes per head stride the edge list)
    float mx = -3.4e38f;
    for (int k = beg + sub; k < end; k += 16) {
        int s = csr_src[k];
        float v = el[s * 4 + h] + er_h;
        v = (v > 0.f) ? v : v * NEG_SLOPE;
        mx = fmaxf(mx, v);
    }
#pragma unroll
    for (int o = 1; o < 16; o <<= 1) mx = fmaxf(mx, __shfl_xor(mx, o));

    // pass 2: exp-sum per head
    float sm = 0.f;
    for (int k = beg + sub; k < end; k += 16) {
        int s = csr_src[k];
        float v = el[s * 4 + h] + er_h;
        v = (v > 0.f) ? v : v * NEG_SLOPE;
        sm += __expf(v - mx);
    }
#pragma unroll
    for (int o = 1; o < 16; o <<= 1) sm += __shfl_xor(sm, o);
    float inv_den = 1.f / fmaxf(sm, 1e-9f);

    // pass 3: weighted gather-accumulate (whole wave walks each edge)
    float2 acc = make_float2(0.f, 0.f);
    for (int k = beg; k < end; ++k) {
        int s = csr_src[k];
        float v = el[s * 4 + h] + er_h;
        v = (v > 0.f) ? v : v * NEG_SLOPE;
        float a = __expf(v - mx) * inv_den;
        float2 f = *(const float2*)(feat + (size_t)s * HD + lane * 2);
        acc.x = fmaf(a, f.x, acc.x);
        acc.y = fmaf(a, f.y, acc.y);
    }
    // head mean: sum over the 4 head groups (lanes L, L^16, L^32, L^48)
    acc.x += __shfl_xor(acc.x, 16);
    acc.y += __shfl_xor(acc.y, 16);
    acc.x += __shfl_xor(acc.x, 32);
    acc.y += __shfl_xor(acc.y, 32);
    if (lane < 16) {
        float2 o = make_float2(acc.x * 0.25f, acc.y * 0.25f);
        *(float2*)(out + (size_t)node * 32 + lane * 2) = o;
    }
}

// ---------------- launch ----------------
extern "C" void kernel_launch(void* const* d_in, const int* in_sizes, int n_in,
                              void* d_out, int out_size, void* d_ws, size_t ws_size,
                              hipStream_t stream) {
    const float* x      = (const float*)d_in[0];
    const float* W      = (const float*)d_in[1];
    const float* attn_l = (const float*)d_in[2];
    const float* attn_r = (const float*)d_in[3];
    const int*   src    = (const int*)d_in[4];
    const int*   dst    = (const int*)d_in[5];
    float* out = (float*)d_out;

    char* p = (char*)d_ws;
    auto alloc = [&](size_t bytes) -> void* {
        void* r = (void*)p;
        p += (bytes + 255) & ~(size_t)255;
        return r;
    };
    float* feat   = (float*)alloc((size_t)NN * HD * 4);
    float* el     = (float*)alloc((size_t)NN * 4 * 4);
    float* er     = (float*)alloc((size_t)NN * 4 * 4);
    int*   offs   = (int*)alloc((size_t)(NN + 1) * 4);
    int*   deg    = (int*)alloc((size_t)NN * 4);
    int*   cursor = (int*)alloc((size_t)NN * 4);
    int*   bsum   = (int*)alloc(64 * 4);
    int*   csr    = (int*)alloc((size_t)NE * 4);

    hipMemsetAsync(deg, 0, (size_t)NN * 4, stream);
    hipMemsetAsync(cursor, 0, (size_t)NN * 4, stream);

    gemm_kernel<<<(NN + 63) / 64, 256, 0, stream>>>(x, W, feat);
    eler_kernel<<<NN / 4, 256, 0, stream>>>(feat, attn_l, attn_r, el, er);
    hist_kernel<<<(NE + 255) / 256, 256, 0, stream>>>(dst, deg);
    scan1_kernel<<<NB_SCAN, 256, 0, stream>>>(deg, offs, bsum);
    scan2_kernel<<<1, 64, 0, stream>>>(bsum, offs);
    scan3_kernel<<<NB_SCAN, 256, 0, stream>>>(offs, bsum);
    fill_csr_kernel<<<(NE + 255) / 256, 256, 0, stream>>>(src, dst, offs, cursor, csr);
    aggregate_kernel<<<NN / 4, 256, 0, stream>>>(feat, el, er, offs, csr, out);
}

// Round 2
// 522.677 us; speedup vs baseline: 1.1386x; 1.1386x over previous
//
#include <hip/hip_runtime.h>
#include <math.h>

#define NN 100000
#define NE 1600000
#define IN_DIM 256
#define HD 128           // HEADS*OUT_DIM
#define NEG_SLOPE 0.2f
#define SCAN_CHUNK 2048
#define NB_SCAN ((NN + SCAN_CHUNK - 1) / SCAN_CHUNK)   // 49

__device__ inline unsigned short f2bf(float f) {
    unsigned int b = __float_as_uint(f);
    b += 0x7fffu + ((b >> 16) & 1u);   // round-to-nearest-even
    return (unsigned short)(b >> 16);
}

// ---- GEMM: feat_bf16[N,128] = bf16(x[N,256] @ W[256,128]); el/er fused ----
__global__ __launch_bounds__(256) void gemm_kernel(const float* __restrict__ x,
                                                   const float* __restrict__ W,
                                                   const float* __restrict__ attn_l,
                                                   const float* __restrict__ attn_r,
                                                   unsigned short* __restrict__ featb,
                                                   float* __restrict__ el,
                                                   float* __restrict__ er) {
    __shared__ float As[16][64];    // A transposed: As[k][row]
    __shared__ float Bs[16][128];
    const int tid = threadIdx.x;
    const int block_row = blockIdx.x * 64;
    const int tx = tid & 31;        // column group (4 cols each)
    const int ty = tid >> 5;        // row group (8 rows each)
    const int arow  = tid >> 2;     // 0..63
    const int acol4 = (tid & 3) << 2;
    const int brow  = tid >> 5;     // 0..7
    const int bcol4 = (tid & 31) << 2;

    float acc[8][4];
#pragma unroll
    for (int r = 0; r < 8; ++r)
#pragma unroll
        for (int c = 0; c < 4; ++c) acc[r][c] = 0.f;

    int grow = block_row + arow;
    if (grow >= NN) grow = NN - 1;              // clamp (stores are guarded)
    const float* xrow = x + (size_t)grow * IN_DIM;

    for (int k0 = 0; k0 < IN_DIM; k0 += 16) {
        float4 av = *(const float4*)(xrow + k0 + acol4);
        As[acol4 + 0][arow] = av.x;
        As[acol4 + 1][arow] = av.y;
        As[acol4 + 2][arow] = av.z;
        As[acol4 + 3][arow] = av.w;
        float4 bv0 = *(const float4*)(W + (size_t)(k0 + brow) * HD + bcol4);
        float4 bv1 = *(const float4*)(W + (size_t)(k0 + brow + 8) * HD + bcol4);
        *(float4*)&Bs[brow][bcol4]     = bv0;
        *(float4*)&Bs[brow + 8][bcol4] = bv1;
        __syncthreads();
#pragma unroll
        for (int kk = 0; kk < 16; ++kk) {
            float4 a0 = *(const float4*)&As[kk][ty * 8];
            float4 a1 = *(const float4*)&As[kk][ty * 8 + 4];
            float4 b  = *(const float4*)&Bs[kk][tx * 4];
            float ar[8] = {a0.x, a0.y, a0.z, a0.w, a1.x, a1.y, a1.z, a1.w};
            float br[4] = {b.x, b.y, b.z, b.w};
#pragma unroll
            for (int r = 0; r < 8; ++r)
#pragma unroll
                for (int c = 0; c < 4; ++c)
                    acc[r][c] = fmaf(ar[r], br[c], acc[r][c]);
        }
        __syncthreads();
    }

    // epilogue: el/er from fp32 accumulators + bf16 feat store
    // cols owned: tx*4..tx*4+3, head h = tx>>3, d = (tx&7)*4+c
    // -> attn index h*32 + (tx&7)*4 + c == tx*4 + c
    float4 al4 = ((const float4*)attn_l)[tx];
    float4 ar4 = ((const float4*)attn_r)[tx];
    int h = tx >> 3;
#pragma unroll
    for (int r = 0; r < 8; ++r) {
        int row = block_row + ty * 8 + r;
        float pl = acc[r][0] * al4.x + acc[r][1] * al4.y + acc[r][2] * al4.z + acc[r][3] * al4.w;
        float pr = acc[r][0] * ar4.x + acc[r][1] * ar4.y + acc[r][2] * ar4.z + acc[r][3] * ar4.w;
#pragma unroll
        for (int o = 1; o < 8; o <<= 1) {
            pl += __shfl_xor(pl, o);
            pr += __shfl_xor(pr, o);
        }
        if (row < NN) {
            ushort4 o4;
            o4.x = f2bf(acc[r][0]); o4.y = f2bf(acc[r][1]);
            o4.z = f2bf(acc[r][2]); o4.w = f2bf(acc[r][3]);
            *(ushort4*)(featb + (size_t)row * HD + tx * 4) = o4;
            if ((tx & 7) == 0) {
                el[row * 4 + h] = pl;
                er[row * 4 + h] = pr;
            }
        }
    }
}

// ---------------- degree histogram ----------------
__global__ void hist_kernel(const int* __restrict__ dst, int* __restrict__ deg) {
    int e = blockIdx.x * blockDim.x + threadIdx.x;
    if (e < NE) atomicAdd(&deg[dst[e]], 1);
}

// ---------------- exclusive scan (3 kernels) ----------------
__global__ __launch_bounds__(256) void scan1_kernel(const int* __restrict__ deg,
                                                    int* __restrict__ offs,
                                                    int* __restrict__ bsum) {
    __shared__ int sh[256];
    int b = blockIdx.x, t = threadIdx.x;
    int base = b * SCAN_CHUNK + t * 8;
    int v[8];
    int s = 0;
#pragma unroll
    for (int j = 0; j < 8; ++j) {
        int i = base + j;
        v[j] = (i < NN) ? deg[i] : 0;
        s += v[j];
    }
    sh[t] = s;
    __syncthreads();
    for (int o = 1; o < 256; o <<= 1) {
        int add = (t >= o) ? sh[t - o] : 0;
        __syncthreads();
        sh[t] += add;
        __syncthreads();
    }
    int incl = sh[t];
    int run = incl - s;   // exclusive within block
#pragma unroll
    for (int j = 0; j < 8; ++j) {
        int i = base + j;
        if (i < NN) offs[i] = run;
        run += v[j];
    }
    if (t == 255) bsum[b] = incl;   // block total
}

__global__ void scan2_kernel(int* __restrict__ bsum, int* __restrict__ offs) {
    int t = threadIdx.x;            // 64 threads, one wave
    int x = (t < NB_SCAN) ? bsum[t] : 0;
    int v = x;
#pragma unroll
    for (int o = 1; o < 64; o <<= 1) {
        int u = __shfl_up(v, o);
        if (t >= o) v += u;
    }
    if (t < NB_SCAN) bsum[t] = v - x;       // exclusive block offset
    if (t == NB_SCAN - 1) offs[NN] = v;     // grand total (== NE)
}

__global__ __launch_bounds__(256) void scan3_kernel(int* __restrict__ offs,
                                                    const int* __restrict__ bsum) {
    int b = blockIdx.x;
    int add = bsum[b];
    if (add == 0) return;
    int base = b * SCAN_CHUNK + threadIdx.x * 8;
#pragma unroll
    for (int j = 0; j < 8; ++j) {
        int i = base + j;
        if (i < NN) offs[i] += add;
    }
}

// ---------------- CSR bucket fill ----------------
__global__ void fill_csr_kernel(const int* __restrict__ src, const int* __restrict__ dst,
                                const int* __restrict__ offs, int* __restrict__ cursor,
                                int* __restrict__ csr_src) {
    int e = blockIdx.x * blockDim.x + threadIdx.x;
    if (e >= NE) return;
    int d = dst[e];
    int p = offs[d] + atomicAdd(&cursor[d], 1);
    csr_src[p] = src[e];
}

// ---------------- per-node softmax + aggregation (bf16 feat gather) -------
// one wave per dst node. lane L: head h=L>>4, features 2L,2L+1
__global__ __launch_bounds__(256) void aggregate_kernel(const unsigned short* __restrict__ featb,
                                                        const float* __restrict__ el,
                                                        const float* __restrict__ er,
                                                        const int* __restrict__ offs,
                                                        const int* __restrict__ csr_src,
                                                        float* __restrict__ out) {
    int node = (blockIdx.x * blockDim.x + threadIdx.x) >> 6;
    int lane = threadIdx.x & 63;
    if (node >= NN) return;
    int beg = offs[node], end = offs[node + 1];
    int h = lane >> 4;

    if (beg == end) {   // zero in-degree -> zeros
        if (lane < 16) *(float2*)(out + (size_t)node * 32 + lane * 2) = make_float2(0.f, 0.f);
        return;
    }

    float er_h = er[node * 4 + h];
    int sub = lane & 15;

    // online softmax stats per head: 16 lanes stride the edge list
    float m = -3.0e38f, sm = 0.f;
    for (int k = beg + sub; k < end; k += 16) {
        int s = csr_src[k];
        float v = el[s * 4 + h] + er_h;
        v = (v > 0.f) ? v : v * NEG_SLOPE;
        if (v > m) {
            sm = sm * __expf(m - v) + 1.f;
            m = v;
        } else {
            sm += __expf(v - m);
        }
    }
#pragma unroll
    for (int o = 1; o < 16; o <<= 1) {
        float mo = __shfl_xor(m, o);
        float so = __shfl_xor(sm, o);
        float mn = fmaxf(m, mo);
        sm = sm * __expf(m - mn) + so * __expf(mo - mn);
        m = mn;
    }
    float inv_den = 1.f / fmaxf(sm, 1e-9f);

    // gather-accumulate: batch csr loads across lanes, shfl-broadcast
    float2 acc = make_float2(0.f, 0.f);
    for (int k0 = beg; k0 < end; k0 += 64) {
        int idx = k0 + lane;
        int sv = (idx < end) ? csr_src[idx] : 0;
        int cnt = min(64, end - k0);
        for (int j = 0; j < cnt; ++j) {
            int s = __shfl(sv, j);
            float v = el[s * 4 + h] + er_h;
            v = (v > 0.f) ? v : v * NEG_SLOPE;
            float a = __expf(v - m) * inv_den;
            unsigned int u = *(const unsigned int*)(featb + (size_t)s * HD + lane * 2);
            float fx = __uint_as_float(u << 16);
            float fy = __uint_as_float(u & 0xffff0000u);
            acc.x = fmaf(a, fx, acc.x);
            acc.y = fmaf(a, fy, acc.y);
        }
    }
    // head mean: sum over the 4 head groups (lanes L, L^16, L^32, L^48)
    acc.x += __shfl_xor(acc.x, 16);
    acc.y += __shfl_xor(acc.y, 16);
    acc.x += __shfl_xor(acc.x, 32);
    acc.y += __shfl_xor(acc.y, 32);
    if (lane < 16) {
        float2 o = make_float2(acc.x * 0.25f, acc.y * 0.25f);
        *(float2*)(out + (size_t)node * 32 + lane * 2) = o;
    }
}

// ---------------- launch ----------------
extern "C" void kernel_launch(void* const* d_in, const int* in_sizes, int n_in,
                              void* d_out, int out_size, void* d_ws, size_t ws_size,
                              hipStream_t stream) {
    const float* x      = (const float*)d_in[0];
    const float* W      = (const float*)d_in[1];
    const float* attn_l = (const float*)d_in[2];
    const float* attn_r = (const float*)d_in[3];
    const int*   src    = (const int*)d_in[4];
    const int*   dst    = (const int*)d_in[5];
    float* out = (float*)d_out;

    char* p = (char*)d_ws;
    auto alloc = [&](size_t bytes) -> void* {
        void* r = (void*)p;
        p += (bytes + 255) & ~(size_t)255;
        return r;
    };
    unsigned short* featb = (unsigned short*)alloc((size_t)NN * HD * 2);
    float* el     = (float*)alloc((size_t)NN * 4 * 4);
    float* er     = (float*)alloc((size_t)NN * 4 * 4);
    int*   offs   = (int*)alloc((size_t)(NN + 1) * 4);
    int*   deg    = (int*)alloc((size_t)NN * 4);
    int*   cursor = (int*)alloc((size_t)NN * 4);
    int*   bsum   = (int*)alloc(64 * 4);
    int*   csr    = (int*)alloc((size_t)NE * 4);

    hipMemsetAsync(deg, 0, (size_t)NN * 4, stream);
    hipMemsetAsync(cursor, 0, (size_t)NN * 4, stream);

    gemm_kernel<<<(NN + 63) / 64, 256, 0, stream>>>(x, W, attn_l, attn_r, featb, el, er);
    hist_kernel<<<(NE + 255) / 256, 256, 0, stream>>>(dst, deg);
    scan1_kernel<<<NB_SCAN, 256, 0, stream>>>(deg, offs, bsum);
    scan2_kernel<<<1, 64, 0, stream>>>(bsum, offs);
    scan3_kernel<<<NB_SCAN, 256, 0, stream>>>(offs, bsum);
    fill_csr_kernel<<<(NE + 255) / 256, 256, 0, stream>>>(src, dst, offs, cursor, csr);
    aggregate_kernel<<<NN / 4, 256, 0, stream>>>(featb, el, er, offs, csr, out);
}

// Round 3
// 490.471 us; speedup vs baseline: 1.2133x; 1.0657x over previous
//
#include <hip/hip_runtime.h>
#include <math.h>

#define NN 100000
#define NE 1600000
#define IN_DIM 256
#define HD 128           // HEADS*OUT_DIM
#define NEG_SLOPE 0.2f
#define SCAN_CHUNK 2048
#define NB_SCAN ((NN + SCAN_CHUNK - 1) / SCAN_CHUNK)   // 49

typedef __attribute__((ext_vector_type(8))) __bf16 bf16x8;
typedef __attribute__((ext_vector_type(4))) float floatx4;

__device__ inline unsigned short f2bf(float f) {
    unsigned int b = __float_as_uint(f);
    b += 0x7fffu + ((b >> 16) & 1u);   // round-to-nearest-even
    return (unsigned short)(b >> 16);
}
__device__ inline unsigned int pk(float lo, float hi) {
    return (unsigned int)f2bf(lo) | ((unsigned int)f2bf(hi) << 16);
}

// ---- prep: swizzle W[256][128] fp32 -> bf16 B-fragments for 16x16x32 MFMA ----
// frag f = (c*8+t)*64+lane holds B[k=c*32+(lane>>4)*8+j][n=t*16+(lane&15)], j=0..7
__global__ __launch_bounds__(256) void prep_w_kernel(const float* __restrict__ W,
                                                     unsigned int* __restrict__ wswz) {
    int g = blockIdx.x * 256 + threadIdx.x;   // 0..4095
    int lane = g & 63;
    int t = (g >> 6) & 7;
    int c = g >> 9;
    int sub = lane & 15, quad = lane >> 4;
    int n = t * 16 + sub;
    int kbase = c * 32 + quad * 8;
    unsigned int ob = (unsigned int)g * 4;
#pragma unroll
    for (int i = 0; i < 4; ++i) {
        float lo = W[(size_t)(kbase + 2 * i) * HD + n];
        float hi = W[(size_t)(kbase + 2 * i + 1) * HD + n];
        wswz[ob + i] = pk(lo, hi);
    }
}

// ---- GEMM (MFMA): feat_bf16 = bf16(x @ W), el/er fused from fp32 acc ----
// feat layout: shorts [row][sub*8 + t]  (t = n-tile, sub = col-within-tile)
__global__ __launch_bounds__(256) void gemm_kernel(const float* __restrict__ x,
                                                   const uint4* __restrict__ wswz,
                                                   const float* __restrict__ attn_l,
                                                   const float* __restrict__ attn_r,
                                                   unsigned short* __restrict__ featb,
                                                   float* __restrict__ el,
                                                   float* __restrict__ er) {
    __shared__ uint4 Bs[4096];                    // 64 KB: all 64 B-fragments
    const int tid = threadIdx.x;
    for (int i = tid; i < 4096; i += 256) Bs[i] = wswz[i];

    const int lane = tid & 63, wv = tid >> 6;
    const int sub = lane & 15, quad = lane >> 4;
    const int row0 = blockIdx.x * 64 + wv * 16;
    int m = row0 + sub;
    if (m >= NN) m = NN - 1;                      // clamp loads; stores guarded
    const float* xp = x + (size_t)m * IN_DIM + quad * 8;

    floatx4 acc[8];
#pragma unroll
    for (int t = 0; t < 8; ++t) acc[t] = (floatx4){0.f, 0.f, 0.f, 0.f};
    __syncthreads();

#pragma unroll
    for (int c = 0; c < 8; ++c) {
        float4 a0 = *(const float4*)(xp + c * 32);
        float4 a1 = *(const float4*)(xp + c * 32 + 4);
        uint4 au;
        au.x = pk(a0.x, a0.y); au.y = pk(a0.z, a0.w);
        au.z = pk(a1.x, a1.y); au.w = pk(a1.z, a1.w);
        bf16x8 af = __builtin_bit_cast(bf16x8, au);
#pragma unroll
        for (int t = 0; t < 8; ++t) {
            bf16x8 bfr = __builtin_bit_cast(bf16x8, Bs[(c * 8 + t) * 64 + lane]);
            acc[t] = __builtin_amdgcn_mfma_f32_16x16x32_bf16(af, bfr, acc[t], 0, 0, 0);
        }
    }

    // attn vectors: col = t*16+sub -> head t>>1, d=(t&1)*16+sub -> flat idx = t*16+sub
    float al[8], ar[8];
#pragma unroll
    for (int t = 0; t < 8; ++t) {
        al[t] = attn_l[t * 16 + sub];
        ar[t] = attn_r[t * 16 + sub];
    }

#pragma unroll
    for (int r = 0; r < 4; ++r) {
        int row = row0 + quad * 4 + r;            // C/D: row = quad*4 + reg
        uint4 fv;
        fv.x = pk(acc[0][r], acc[1][r]);
        fv.y = pk(acc[2][r], acc[3][r]);
        fv.z = pk(acc[4][r], acc[5][r]);
        fv.w = pk(acc[6][r], acc[7][r]);
        float pl[4], pr[4];
#pragma unroll
        for (int hh = 0; hh < 4; ++hh) {
            pl[hh] = acc[2 * hh][r] * al[2 * hh] + acc[2 * hh + 1][r] * al[2 * hh + 1];
            pr[hh] = acc[2 * hh][r] * ar[2 * hh] + acc[2 * hh + 1][r] * ar[2 * hh + 1];
        }
#pragma unroll
        for (int o = 1; o < 16; o <<= 1) {
#pragma unroll
            for (int hh = 0; hh < 4; ++hh) {
                pl[hh] += __shfl_xor(pl[hh], o);
                pr[hh] += __shfl_xor(pr[hh], o);
            }
        }
        if (row < NN) {
            *(uint4*)(featb + (size_t)row * HD + sub * 8) = fv;
            if (sub < 4) {
                float vl = (sub == 0) ? pl[0] : (sub == 1) ? pl[1] : (sub == 2) ? pl[2] : pl[3];
                float vr = (sub == 0) ? pr[0] : (sub == 1) ? pr[1] : (sub == 2) ? pr[2] : pr[3];
                el[row * 4 + sub] = vl;
                er[row * 4 + sub] = vr;
            }
        }
    }
}

// ---------------- degree histogram ----------------
__global__ void hist_kernel(const int* __restrict__ dst, int* __restrict__ deg) {
    int e = blockIdx.x * blockDim.x + threadIdx.x;
    if (e < NE) atomicAdd(&deg[dst[e]], 1);
}

// ---------------- exclusive scan (3 kernels) ----------------
__global__ __launch_bounds__(256) void scan1_kernel(const int* __restrict__ deg,
                                                    int* __restrict__ offs,
                                                    int* __restrict__ bsum) {
    __shared__ int sh[256];
    int b = blockIdx.x, t = threadIdx.x;
    int base = b * SCAN_CHUNK + t * 8;
    int v[8];
    int s = 0;
#pragma unroll
    for (int j = 0; j < 8; ++j) {
        int i = base + j;
        v[j] = (i < NN) ? deg[i] : 0;
        s += v[j];
    }
    sh[t] = s;
    __syncthreads();
    for (int o = 1; o < 256; o <<= 1) {
        int add = (t >= o) ? sh[t - o] : 0;
        __syncthreads();
        sh[t] += add;
        __syncthreads();
    }
    int incl = sh[t];
    int run = incl - s;
#pragma unroll
    for (int j = 0; j < 8; ++j) {
        int i = base + j;
        if (i < NN) offs[i] = run;
        run += v[j];
    }
    if (t == 255) bsum[b] = incl;
}

__global__ void scan2_kernel(int* __restrict__ bsum, int* __restrict__ offs) {
    int t = threadIdx.x;
    int x = (t < NB_SCAN) ? bsum[t] : 0;
    int v = x;
#pragma unroll
    for (int o = 1; o < 64; o <<= 1) {
        int u = __shfl_up(v, o);
        if (t >= o) v += u;
    }
    if (t < NB_SCAN) bsum[t] = v - x;
    if (t == NB_SCAN - 1) offs[NN] = v;
}

__global__ __launch_bounds__(256) void scan3_kernel(int* __restrict__ offs,
                                                    const int* __restrict__ bsum) {
    int b = blockIdx.x;
    int add = bsum[b];
    if (add == 0) return;
    int base = b * SCAN_CHUNK + threadIdx.x * 8;
#pragma unroll
    for (int j = 0; j < 8; ++j) {
        int i = base + j;
        if (i < NN) offs[i] += add;
    }
}

// ---------------- CSR bucket fill ----------------
__global__ void fill_csr_kernel(const int* __restrict__ src, const int* __restrict__ dst,
                                const int* __restrict__ offs, int* __restrict__ cursor,
                                int* __restrict__ csr_src) {
    int e = blockIdx.x * blockDim.x + threadIdx.x;
    if (e >= NE) return;
    int d = dst[e];
    int p = offs[d] + atomicAdd(&cursor[d], 1);
    csr_src[p] = src[e];
}

// ---------------- softmax + aggregation ----------------
// lane L: head h=L&3, q=L>>2. feat layout [row][sub*8+t] -> uint idx row*64+L
// gives lane L cols (t=2h, d=q) and (t=2h+1, d=16+q) of ITS head.
__global__ __launch_bounds__(256) void aggregate_kernel(const unsigned int* __restrict__ featu,
                                                        const float* __restrict__ el,
                                                        const float* __restrict__ er,
                                                        const int* __restrict__ offs,
                                                        const int* __restrict__ csr_src,
                                                        float* __restrict__ out) {
    int node = (blockIdx.x * blockDim.x + threadIdx.x) >> 6;
    int lane = threadIdx.x & 63;
    if (node >= NN) return;
    int h = lane & 3, q = lane >> 2;
    int beg = offs[node], end = offs[node + 1];

    if (beg == end) {
        if (h == 0) {
            out[node * 32 + q] = 0.f;
            out[node * 32 + 16 + q] = 0.f;
        }
        return;
    }

    float er_h = er[node * 4 + h];

    // denominator (no max-subtraction: logits bounded ~|10|, exp safe in fp32)
    float sm = 0.f;
    for (int k = beg + q; k < end; k += 16) {
        int s = csr_src[k];
        float v = el[s * 4 + h] + er_h;
        v = (v > 0.f) ? v : v * NEG_SLOPE;
        sm += __expf(v);
    }
    sm += __shfl_xor(sm, 4);
    sm += __shfl_xor(sm, 8);
    sm += __shfl_xor(sm, 16);
    sm += __shfl_xor(sm, 32);
    float inv_den = 1.f / fmaxf(sm, 1e-9f);

    float accx = 0.f, accy = 0.f;
    for (int k0 = beg; k0 < end; k0 += 64) {
        int cnt = min(64, end - k0);
        int sv = (lane < cnt) ? csr_src[k0 + lane] : 0;
        // phase A: lane computes 4 weights (its head, edges q*4..q*4+3)
        float aval[4];
#pragma unroll
        for (int i = 0; i < 4; ++i) {
            int j = q * 4 + i;
            int s = __shfl(sv, j);
            float v = el[s * 4 + h] + er_h;
            v = (v > 0.f) ? v : v * NEG_SLOPE;
            aval[i] = (j < cnt) ? __expf(v) * inv_den : 0.f;
        }
        // phase B: per edge j, weight lives in lane (j&~3)+h, slot j&3
        for (int j0 = 0; j0 < cnt; j0 += 4) {
#pragma unroll
            for (int i = 0; i < 4; ++i) {
                int j = j0 + i;
                if (j < cnt) {
                    int s = __shfl(sv, j);
                    float a = __shfl(aval[i], (j & ~3) + h);
                    unsigned int u = featu[(size_t)s * 64 + lane];
                    accx = fmaf(a, __uint_as_float(u << 16), accx);
                    accy = fmaf(a, __uint_as_float(u & 0xffff0000u), accy);
                }
            }
        }
    }
    // head mean: reduce across h (lane bits 0..1)
    accx += __shfl_xor(accx, 1); accy += __shfl_xor(accy, 1);
    accx += __shfl_xor(accx, 2); accy += __shfl_xor(accy, 2);
    if (h == 0) {
        out[node * 32 + q]      = accx * 0.25f;
        out[node * 32 + 16 + q] = accy * 0.25f;
    }
}

// ---------------- launch ----------------
extern "C" void kernel_launch(void* const* d_in, const int* in_sizes, int n_in,
                              void* d_out, int out_size, void* d_ws, size_t ws_size,
                              hipStream_t stream) {
    const float* x      = (const float*)d_in[0];
    const float* W      = (const float*)d_in[1];
    const float* attn_l = (const float*)d_in[2];
    const float* attn_r = (const float*)d_in[3];
    const int*   src    = (const int*)d_in[4];
    const int*   dst    = (const int*)d_in[5];
    float* out = (float*)d_out;

    char* p = (char*)d_ws;
    auto alloc = [&](size_t bytes) -> void* {
        void* r = (void*)p;
        p += (bytes + 255) & ~(size_t)255;
        return r;
    };
    unsigned short* featb = (unsigned short*)alloc((size_t)NN * HD * 2);
    unsigned int*   wswz  = (unsigned int*)alloc(4096 * 16);
    float* el     = (float*)alloc((size_t)NN * 4 * 4);
    float* er     = (float*)alloc((size_t)NN * 4 * 4);
    int*   offs   = (int*)alloc((size_t)(NN + 1) * 4);
    int*   deg    = (int*)alloc((size_t)NN * 4);
    int*   cursor = (int*)alloc((size_t)NN * 4);
    int*   bsum   = (int*)alloc(64 * 4);
    int*   csr    = (int*)alloc((size_t)NE * 4);

    hipMemsetAsync(deg, 0, (size_t)NN * 4, stream);
    hipMemsetAsync(cursor, 0, (size_t)NN * 4, stream);

    prep_w_kernel<<<16, 256, 0, stream>>>(W, wswz);
    gemm_kernel<<<(NN + 63) / 64, 256, 0, stream>>>(x, (const uint4*)wswz, attn_l, attn_r,
                                                    featb, el, er);
    hist_kernel<<<(NE + 255) / 256, 256, 0, stream>>>(dst, deg);
    scan1_kernel<<<NB_SCAN, 256, 0, stream>>>(deg, offs, bsum);
    scan2_kernel<<<1, 64, 0, stream>>>(bsum, offs);
    scan3_kernel<<<NB_SCAN, 256, 0, stream>>>(offs, bsum);
    fill_csr_kernel<<<(NE + 255) / 256, 256, 0, stream>>>(src, dst, offs, cursor, csr);
    aggregate_kernel<<<NN / 4, 256, 0, stream>>>((const unsigned int*)featb, el, er, offs, csr, out);
}

// Round 4
// 416.293 us; speedup vs baseline: 1.4295x; 1.1782x over previous
//
#include <hip/hip_runtime.h>
#include <math.h>

#define NN 100000
#define NE 1600000
#define IN_DIM 256
#define HD 128           // HEADS*OUT_DIM
#define NEG_SLOPE 0.2f
#define SCAN_CHUNK 2048
#define NB_SCAN ((NN + SCAN_CHUNK - 1) / SCAN_CHUNK)   // 49

typedef __attribute__((ext_vector_type(8))) __bf16 bf16x8;
typedef __attribute__((ext_vector_type(4))) float floatx4;

__device__ inline unsigned short f2bf(float f) {
    unsigned int b = __float_as_uint(f);
    b += 0x7fffu + ((b >> 16) & 1u);   // round-to-nearest-even
    return (unsigned short)(b >> 16);
}
__device__ inline unsigned int pk(float lo, float hi) {
    return (unsigned int)f2bf(lo) | ((unsigned int)f2bf(hi) << 16);
}
__device__ inline float bflo(unsigned int u) { return __uint_as_float(u << 16); }
__device__ inline float bfhi(unsigned int u) { return __uint_as_float(u & 0xffff0000u); }
__device__ inline float lrelu(float v) { return (v > 0.f) ? v : v * NEG_SLOPE; }

// ---- prep: swizzle W[256][128] fp32 -> bf16 B-fragments for 16x16x32 MFMA ----
// frag f = (c*8+t)*64+lane holds B[k=c*32+(lane>>4)*8+j][n=t*16+(lane&15)], j=0..7
__global__ __launch_bounds__(256) void prep_w_kernel(const float* __restrict__ W,
                                                     unsigned int* __restrict__ wswz) {
    int g = blockIdx.x * 256 + threadIdx.x;   // 0..4095
    int lane = g & 63;
    int t = (g >> 6) & 7;
    int c = g >> 9;
    int sub = lane & 15, quad = lane >> 4;
    int n = t * 16 + sub;
    int kbase = c * 32 + quad * 8;
    unsigned int ob = (unsigned int)g * 4;
#pragma unroll
    for (int i = 0; i < 4; ++i) {
        float lo = W[(size_t)(kbase + 2 * i) * HD + n];
        float hi = W[(size_t)(kbase + 2 * i + 1) * HD + n];
        wswz[ob + i] = pk(lo, hi);
    }
}

// ---- GEMM (MFMA): feat_bf16 = bf16(x @ W), el/er fused from fp32 acc ----
// feat layout: shorts [row][sub*8 + t]  (t = n-tile, sub = col-within-tile)
__global__ __launch_bounds__(256) void gemm_kernel(const float* __restrict__ x,
                                                   const uint4* __restrict__ wswz,
                                                   const float* __restrict__ attn_l,
                                                   const float* __restrict__ attn_r,
                                                   unsigned short* __restrict__ featb,
                                                   float* __restrict__ el,
                                                   float* __restrict__ er) {
    __shared__ uint4 Bs[4096];                    // 64 KB: all 64 B-fragments
    const int tid = threadIdx.x;
    for (int i = tid; i < 4096; i += 256) Bs[i] = wswz[i];

    const int lane = tid & 63, wv = tid >> 6;
    const int sub = lane & 15, quad = lane >> 4;
    const int row0 = blockIdx.x * 64 + wv * 16;
    int m = row0 + sub;
    if (m >= NN) m = NN - 1;                      // clamp loads; stores guarded
    const float* xp = x + (size_t)m * IN_DIM + quad * 8;

    floatx4 acc[8];
#pragma unroll
    for (int t = 0; t < 8; ++t) acc[t] = (floatx4){0.f, 0.f, 0.f, 0.f};
    __syncthreads();

#pragma unroll
    for (int c = 0; c < 8; ++c) {
        float4 a0 = *(const float4*)(xp + c * 32);
        float4 a1 = *(const float4*)(xp + c * 32 + 4);
        uint4 au;
        au.x = pk(a0.x, a0.y); au.y = pk(a0.z, a0.w);
        au.z = pk(a1.x, a1.y); au.w = pk(a1.z, a1.w);
        bf16x8 af = __builtin_bit_cast(bf16x8, au);
#pragma unroll
        for (int t = 0; t < 8; ++t) {
            bf16x8 bfr = __builtin_bit_cast(bf16x8, Bs[(c * 8 + t) * 64 + lane]);
            acc[t] = __builtin_amdgcn_mfma_f32_16x16x32_bf16(af, bfr, acc[t], 0, 0, 0);
        }
    }

    // attn vectors: col = t*16+sub -> flat idx = t*16+sub
    float al[8], ar[8];
#pragma unroll
    for (int t = 0; t < 8; ++t) {
        al[t] = attn_l[t * 16 + sub];
        ar[t] = attn_r[t * 16 + sub];
    }

#pragma unroll
    for (int r = 0; r < 4; ++r) {
        int row = row0 + quad * 4 + r;            // C/D: row = quad*4 + reg
        uint4 fv;
        fv.x = pk(acc[0][r], acc[1][r]);
        fv.y = pk(acc[2][r], acc[3][r]);
        fv.z = pk(acc[4][r], acc[5][r]);
        fv.w = pk(acc[6][r], acc[7][r]);
        float pl[4], pr[4];
#pragma unroll
        for (int hh = 0; hh < 4; ++hh) {
            pl[hh] = acc[2 * hh][r] * al[2 * hh] + acc[2 * hh + 1][r] * al[2 * hh + 1];
            pr[hh] = acc[2 * hh][r] * ar[2 * hh] + acc[2 * hh + 1][r] * ar[2 * hh + 1];
        }
#pragma unroll
        for (int o = 1; o < 16; o <<= 1) {
#pragma unroll
            for (int hh = 0; hh < 4; ++hh) {
                pl[hh] += __shfl_xor(pl[hh], o);
                pr[hh] += __shfl_xor(pr[hh], o);
            }
        }
        if (row < NN) {
            *(uint4*)(featb + (size_t)row * HD + sub * 8) = fv;
            if (sub < 4) {
                float vl = (sub == 0) ? pl[0] : (sub == 1) ? pl[1] : (sub == 2) ? pl[2] : pl[3];
                float vr = (sub == 0) ? pr[0] : (sub == 1) ? pr[1] : (sub == 2) ? pr[2] : pr[3];
                el[row * 4 + sub] = vl;
                er[row * 4 + sub] = vr;
            }
        }
    }
}

// ---------------- degree histogram ----------------
__global__ void hist_kernel(const int* __restrict__ dst, int* __restrict__ deg) {
    int e = blockIdx.x * blockDim.x + threadIdx.x;
    if (e < NE) atomicAdd(&deg[dst[e]], 1);
}

// ---------------- exclusive scan (3 kernels) ----------------
__global__ __launch_bounds__(256) void scan1_kernel(const int* __restrict__ deg,
                                                    int* __restrict__ offs,
                                                    int* __restrict__ bsum) {
    __shared__ int sh[256];
    int b = blockIdx.x, t = threadIdx.x;
    int base = b * SCAN_CHUNK + t * 8;
    int v[8];
    int s = 0;
#pragma unroll
    for (int j = 0; j < 8; ++j) {
        int i = base + j;
        v[j] = (i < NN) ? deg[i] : 0;
        s += v[j];
    }
    sh[t] = s;
    __syncthreads();
    for (int o = 1; o < 256; o <<= 1) {
        int add = (t >= o) ? sh[t - o] : 0;
        __syncthreads();
        sh[t] += add;
        __syncthreads();
    }
    int incl = sh[t];
    int run = incl - s;
#pragma unroll
    for (int j = 0; j < 8; ++j) {
        int i = base + j;
        if (i < NN) offs[i] = run;
        run += v[j];
    }
    if (t == 255) bsum[b] = incl;
}

__global__ void scan2_kernel(int* __restrict__ bsum, int* __restrict__ offs) {
    int t = threadIdx.x;
    int x = (t < NB_SCAN) ? bsum[t] : 0;
    int v = x;
#pragma unroll
    for (int o = 1; o < 64; o <<= 1) {
        int u = __shfl_up(v, o);
        if (t >= o) v += u;
    }
    if (t < NB_SCAN) bsum[t] = v - x;
    if (t == NB_SCAN - 1) offs[NN] = v;
}

__global__ __launch_bounds__(256) void scan3_kernel(int* __restrict__ offs,
                                                    const int* __restrict__ bsum) {
    int b = blockIdx.x;
    int add = bsum[b];
    if (add == 0) return;
    int base = b * SCAN_CHUNK + threadIdx.x * 8;
#pragma unroll
    for (int j = 0; j < 8; ++j) {
        int i = base + j;
        if (i < NN) offs[i] += add;
    }
}

// ---------------- CSR bucket fill ----------------
__global__ void fill_csr_kernel(const int* __restrict__ src, const int* __restrict__ dst,
                                const int* __restrict__ offs, int* __restrict__ cursor,
                                int* __restrict__ csr_src) {
    int e = blockIdx.x * blockDim.x + threadIdx.x;
    if (e >= NE) return;
    int d = dst[e];
    int p = offs[d] + atomicAdd(&cursor[d], 1);
    csr_src[p] = src[e];
}

// ---------------- softmax + aggregation (single pass) ----------------
// one wave = 4 nodes; 16 lanes per node. lane sub owns cols (d=sub, d=16+sub)
// of all 4 heads: uint4 at featu4[s*16+sub] = {h0,h1,h2,h3}, lo16=d=sub, hi16=d=16+sub.
// Per 32-edge chunk: stage (s, w4=exp(leaky(el4[s]+er4))) in LDS (distinct lanes
// compute distinct edges -> 4 exp/edge total), accumulate per-head unnormalized
// sums + denominators, normalize in epilogue.
#define CH 32
__global__ __launch_bounds__(256) void aggregate_kernel(const uint4* __restrict__ featu4,
                                                        const float4* __restrict__ el4,
                                                        const float4* __restrict__ er4,
                                                        const int* __restrict__ offs,
                                                        const int* __restrict__ csr_src,
                                                        float* __restrict__ out) {
    __shared__ int    s_sv[4][4][CH];
    __shared__ float4 s_a4[4][4][CH];

    const int tid = threadIdx.x;
    const int lane = tid & 63, wv = tid >> 6;
    const int g = lane >> 4, sub = lane & 15;
    const int node = blockIdx.x * 16 + wv * 4 + g;   // NN == 6250*16 exactly
    const int beg = offs[node], end = offs[node + 1];

    const float4 erv = er4[node];
    float4 sm = make_float4(0.f, 0.f, 0.f, 0.f);
    float acc[8];
#pragma unroll
    for (int i = 0; i < 8; ++i) acc[i] = 0.f;

    for (int c0 = beg; c0 < end; c0 += CH) {
        int cnt = end - c0;
        if (cnt > CH) cnt = CH;
        // stage weights: lane handles slots sub and sub+16
#pragma unroll
        for (int t = 0; t < 2; ++t) {
            int slot = sub + t * 16;
            if (slot < cnt) {
                int s = csr_src[c0 + slot];
                float4 e = el4[s];
                float4 w;
                w.x = __expf(lrelu(e.x + erv.x));
                w.y = __expf(lrelu(e.y + erv.y));
                w.z = __expf(lrelu(e.z + erv.z));
                w.w = __expf(lrelu(e.w + erv.w));
                sm.x += w.x; sm.y += w.y; sm.z += w.z; sm.w += w.w;
                s_sv[wv][g][slot] = s;
                s_a4[wv][g][slot] = w;
            }
        }
        // gather: unroll 4 for MLP (4 dwordx4 loads in flight)
        int j = 0;
        for (; j + 4 <= cnt; j += 4) {
            int s0 = s_sv[wv][g][j + 0];
            int s1 = s_sv[wv][g][j + 1];
            int s2 = s_sv[wv][g][j + 2];
            int s3 = s_sv[wv][g][j + 3];
            uint4 u0 = featu4[(size_t)s0 * 16 + sub];
            uint4 u1 = featu4[(size_t)s1 * 16 + sub];
            uint4 u2 = featu4[(size_t)s2 * 16 + sub];
            uint4 u3 = featu4[(size_t)s3 * 16 + sub];
            float4 w0 = s_a4[wv][g][j + 0];
            float4 w1 = s_a4[wv][g][j + 1];
            float4 w2 = s_a4[wv][g][j + 2];
            float4 w3 = s_a4[wv][g][j + 3];
            acc[0] = fmaf(w0.x, bflo(u0.x), acc[0]); acc[1] = fmaf(w0.x, bfhi(u0.x), acc[1]);
            acc[2] = fmaf(w0.y, bflo(u0.y), acc[2]); acc[3] = fmaf(w0.y, bfhi(u0.y), acc[3]);
            acc[4] = fmaf(w0.z, bflo(u0.z), acc[4]); acc[5] = fmaf(w0.z, bfhi(u0.z), acc[5]);
            acc[6] = fmaf(w0.w, bflo(u0.w), acc[6]); acc[7] = fmaf(w0.w, bfhi(u0.w), acc[7]);
            acc[0] = fmaf(w1.x, bflo(u1.x), acc[0]); acc[1] = fmaf(w1.x, bfhi(u1.x), acc[1]);
            acc[2] = fmaf(w1.y, bflo(u1.y), acc[2]); acc[3] = fmaf(w1.y, bfhi(u1.y), acc[3]);
            acc[4] = fmaf(w1.z, bflo(u1.z), acc[4]); acc[5] = fmaf(w1.z, bfhi(u1.z), acc[5]);
            acc[6] = fmaf(w1.w, bflo(u1.w), acc[6]); acc[7] = fmaf(w1.w, bfhi(u1.w), acc[7]);
            acc[0] = fmaf(w2.x, bflo(u2.x), acc[0]); acc[1] = fmaf(w2.x, bfhi(u2.x), acc[1]);
            acc[2] = fmaf(w2.y, bflo(u2.y), acc[2]); acc[3] = fmaf(w2.y, bfhi(u2.y), acc[3]);
            acc[4] = fmaf(w2.z, bflo(u2.z), acc[4]); acc[5] = fmaf(w2.z, bfhi(u2.z), acc[5]);
            acc[6] = fmaf(w2.w, bflo(u2.w), acc[6]); acc[7] = fmaf(w2.w, bfhi(u2.w), acc[7]);
            acc[0] = fmaf(w3.x, bflo(u3.x), acc[0]); acc[1] = fmaf(w3.x, bfhi(u3.x), acc[1]);
            acc[2] = fmaf(w3.y, bflo(u3.y), acc[2]); acc[3] = fmaf(w3.y, bfhi(u3.y), acc[3]);
            acc[4] = fmaf(w3.z, bflo(u3.z), acc[4]); acc[5] = fmaf(w3.z, bfhi(u3.z), acc[5]);
            acc[6] = fmaf(w3.w, bflo(u3.w), acc[6]); acc[7] = fmaf(w3.w, bfhi(u3.w), acc[7]);
        }
        for (; j < cnt; ++j) {
            int s = s_sv[wv][g][j];
            uint4 u = featu4[(size_t)s * 16 + sub];
            float4 w = s_a4[wv][g][j];
            acc[0] = fmaf(w.x, bflo(u.x), acc[0]); acc[1] = fmaf(w.x, bfhi(u.x), acc[1]);
            acc[2] = fmaf(w.y, bflo(u.y), acc[2]); acc[3] = fmaf(w.y, bfhi(u.y), acc[3]);
            acc[4] = fmaf(w.z, bflo(u.z), acc[4]); acc[5] = fmaf(w.z, bfhi(u.z), acc[5]);
            acc[6] = fmaf(w.w, bflo(u.w), acc[6]); acc[7] = fmaf(w.w, bfhi(u.w), acc[7]);
        }
    }

    // reduce denominators across the 16 lanes of this node
#pragma unroll
    for (int o = 1; o < 16; o <<= 1) {
        sm.x += __shfl_xor(sm.x, o);
        sm.y += __shfl_xor(sm.y, o);
        sm.z += __shfl_xor(sm.z, o);
        sm.w += __shfl_xor(sm.w, o);
    }
    float ix = 1.f / fmaxf(sm.x, 1e-9f);
    float iy = 1.f / fmaxf(sm.y, 1e-9f);
    float iz = 1.f / fmaxf(sm.z, 1e-9f);
    float iw = 1.f / fmaxf(sm.w, 1e-9f);
    float ox = 0.25f * (acc[0] * ix + acc[2] * iy + acc[4] * iz + acc[6] * iw);
    float oy = 0.25f * (acc[1] * ix + acc[3] * iy + acc[5] * iz + acc[7] * iw);
    out[node * 32 + sub]      = ox;
    out[node * 32 + 16 + sub] = oy;
}

// ---------------- launch ----------------
extern "C" void kernel_launch(void* const* d_in, const int* in_sizes, int n_in,
                              void* d_out, int out_size, void* d_ws, size_t ws_size,
                              hipStream_t stream) {
    const float* x      = (const float*)d_in[0];
    const float* W      = (const float*)d_in[1];
    const float* attn_l = (const float*)d_in[2];
    const float* attn_r = (const float*)d_in[3];
    const int*   src    = (const int*)d_in[4];
    const int*   dst    = (const int*)d_in[5];
    float* out = (float*)d_out;

    char* p = (char*)d_ws;
    auto alloc = [&](size_t bytes) -> void* {
        void* r = (void*)p;
        p += (bytes + 255) & ~(size_t)255;
        return r;
    };
    unsigned short* featb = (unsigned short*)alloc((size_t)NN * HD * 2);
    unsigned int*   wswz  = (unsigned int*)alloc(4096 * 16);
    float* el     = (float*)alloc((size_t)NN * 4 * 4);
    float* er     = (float*)alloc((size_t)NN * 4 * 4);
    int*   offs   = (int*)alloc((size_t)(NN + 1) * 4);
    int*   deg    = (int*)alloc((size_t)NN * 4);
    int*   cursor = (int*)alloc((size_t)NN * 4);
    int*   bsum   = (int*)alloc(64 * 4);
    int*   csr    = (int*)alloc((size_t)NE * 4);

    hipMemsetAsync(deg, 0, (size_t)NN * 4, stream);
    hipMemsetAsync(cursor, 0, (size_t)NN * 4, stream);

    prep_w_kernel<<<16, 256, 0, stream>>>(W, wswz);
    gemm_kernel<<<(NN + 63) / 64, 256, 0, stream>>>(x, (const uint4*)wswz, attn_l, attn_r,
                                                    featb, el, er);
    hist_kernel<<<(NE + 255) / 256, 256, 0, stream>>>(dst, deg);
    scan1_kernel<<<NB_SCAN, 256, 0, stream>>>(deg, offs, bsum);
    scan2_kernel<<<1, 64, 0, stream>>>(bsum, offs);
    scan3_kernel<<<NB_SCAN, 256, 0, stream>>>(offs, bsum);
    fill_csr_kernel<<<(NE + 255) / 256, 256, 0, stream>>>(src, dst, offs, cursor, csr);
    aggregate_kernel<<<NN / 16, 256, 0, stream>>>((const uint4*)featb, (const float4*)el,
                                                  (const float4*)er, offs, csr, out);
}

// Round 5
// 375.953 us; speedup vs baseline: 1.5829x; 1.1073x over previous
//
#include <hip/hip_runtime.h>
#include <math.h>

#define NN 100000
#define NE 1600000
#define IN_DIM 256
#define HD 128           // HEADS*OUT_DIM
#define NEG_SLOPE 0.2f
#define SCAN_CHUNK 2048
#define NB_SCAN ((NN + SCAN_CHUNK - 1) / SCAN_CHUNK)   // 49

typedef __attribute__((ext_vector_type(8))) __bf16 bf16x8;
typedef __attribute__((ext_vector_type(4))) float floatx4;

__device__ inline unsigned short f2bf(float f) {
    unsigned int b = __float_as_uint(f);
    b += 0x7fffu + ((b >> 16) & 1u);   // round-to-nearest-even
    return (unsigned short)(b >> 16);
}
__device__ inline unsigned int pk(float lo, float hi) {
    return (unsigned int)f2bf(lo) | ((unsigned int)f2bf(hi) << 16);
}
__device__ inline float bflo(unsigned int u) { return __uint_as_float(u << 16); }
__device__ inline float bfhi(unsigned int u) { return __uint_as_float(u & 0xffff0000u); }
__device__ inline float lrelu(float v) { return (v > 0.f) ? v : v * NEG_SLOPE; }

// ---- prep: swizzle W[256][128] fp32 -> bf16 B-fragments for 16x16x32 MFMA ----
// frag f = (c*8+t)*64+lane holds B[k=c*32+(lane>>4)*8+j][n=t*16+(lane&15)], j=0..7
__global__ __launch_bounds__(256) void prep_w_kernel(const float* __restrict__ W,
                                                     unsigned int* __restrict__ wswz) {
    int g = blockIdx.x * 256 + threadIdx.x;   // 0..4095
    int lane = g & 63;
    int t = (g >> 6) & 7;
    int c = g >> 9;
    int sub = lane & 15, quad = lane >> 4;
    int n = t * 16 + sub;
    int kbase = c * 32 + quad * 8;
    unsigned int ob = (unsigned int)g * 4;
#pragma unroll
    for (int i = 0; i < 4; ++i) {
        float lo = W[(size_t)(kbase + 2 * i) * HD + n];
        float hi = W[(size_t)(kbase + 2 * i + 1) * HD + n];
        wswz[ob + i] = pk(lo, hi);
    }
}

// ---- GEMM (MFMA): feat_bf16 = bf16(x @ W), el/er fused from fp32 acc ----
// feat layout: shorts [row][sub*8 + t]  (t = n-tile, sub = col-within-tile)
__global__ __launch_bounds__(256) void gemm_kernel(const float* __restrict__ x,
                                                   const uint4* __restrict__ wswz,
                                                   const float* __restrict__ attn_l,
                                                   const float* __restrict__ attn_r,
                                                   unsigned short* __restrict__ featb,
                                                   float* __restrict__ el,
                                                   float* __restrict__ er) {
    __shared__ uint4 Bs[4096];                    // 64 KB: all 64 B-fragments
    const int tid = threadIdx.x;
    for (int i = tid; i < 4096; i += 256) Bs[i] = wswz[i];

    const int lane = tid & 63, wv = tid >> 6;
    const int sub = lane & 15, quad = lane >> 4;
    const int row0 = blockIdx.x * 64 + wv * 16;
    int m = row0 + sub;
    if (m >= NN) m = NN - 1;                      // clamp loads; stores guarded
    const float* xp = x + (size_t)m * IN_DIM + quad * 8;

    floatx4 acc[8];
#pragma unroll
    for (int t = 0; t < 8; ++t) acc[t] = (floatx4){0.f, 0.f, 0.f, 0.f};
    __syncthreads();

#pragma unroll
    for (int c = 0; c < 8; ++c) {
        float4 a0 = *(const float4*)(xp + c * 32);
        float4 a1 = *(const float4*)(xp + c * 32 + 4);
        uint4 au;
        au.x = pk(a0.x, a0.y); au.y = pk(a0.z, a0.w);
        au.z = pk(a1.x, a1.y); au.w = pk(a1.z, a1.w);
        bf16x8 af = __builtin_bit_cast(bf16x8, au);
#pragma unroll
        for (int t = 0; t < 8; ++t) {
            bf16x8 bfr = __builtin_bit_cast(bf16x8, Bs[(c * 8 + t) * 64 + lane]);
            acc[t] = __builtin_amdgcn_mfma_f32_16x16x32_bf16(af, bfr, acc[t], 0, 0, 0);
        }
    }

    // attn vectors: col = t*16+sub -> flat idx = t*16+sub
    float al[8], ar[8];
#pragma unroll
    for (int t = 0; t < 8; ++t) {
        al[t] = attn_l[t * 16 + sub];
        ar[t] = attn_r[t * 16 + sub];
    }

#pragma unroll
    for (int r = 0; r < 4; ++r) {
        int row = row0 + quad * 4 + r;            // C/D: row = quad*4 + reg
        uint4 fv;
        fv.x = pk(acc[0][r], acc[1][r]);
        fv.y = pk(acc[2][r], acc[3][r]);
        fv.z = pk(acc[4][r], acc[5][r]);
        fv.w = pk(acc[6][r], acc[7][r]);
        float pl[4], pr[4];
#pragma unroll
        for (int hh = 0; hh < 4; ++hh) {
            pl[hh] = acc[2 * hh][r] * al[2 * hh] + acc[2 * hh + 1][r] * al[2 * hh + 1];
            pr[hh] = acc[2 * hh][r] * ar[2 * hh] + acc[2 * hh + 1][r] * ar[2 * hh + 1];
        }
#pragma unroll
        for (int o = 1; o < 16; o <<= 1) {
#pragma unroll
            for (int hh = 0; hh < 4; ++hh) {
                pl[hh] += __shfl_xor(pl[hh], o);
                pr[hh] += __shfl_xor(pr[hh], o);
            }
        }
        if (row < NN) {
            *(uint4*)(featb + (size_t)row * HD + sub * 8) = fv;
            if (sub < 4) {
                float vl = (sub == 0) ? pl[0] : (sub == 1) ? pl[1] : (sub == 2) ? pl[2] : pl[3];
                float vr = (sub == 0) ? pr[0] : (sub == 1) ? pr[1] : (sub == 2) ? pr[2] : pr[3];
                el[row * 4 + sub] = vl;
                er[row * 4 + sub] = vr;
            }
        }
    }
}

// ---- degree histogram + rank (8 edges/thread, coalesced rank write) ----
__global__ __launch_bounds__(256) void hist_kernel(const int4* __restrict__ dst4,
                                                   int* __restrict__ deg,
                                                   int4* __restrict__ rank4) {
    int t = blockIdx.x * 256 + threadIdx.x;     // group of 8 edges
    if (t >= NE / 8) return;
    int4 d0 = dst4[t * 2];
    int4 d1 = dst4[t * 2 + 1];
    int4 r0, r1;
    r0.x = atomicAdd(&deg[d0.x], 1);
    r0.y = atomicAdd(&deg[d0.y], 1);
    r0.z = atomicAdd(&deg[d0.z], 1);
    r0.w = atomicAdd(&deg[d0.w], 1);
    r1.x = atomicAdd(&deg[d1.x], 1);
    r1.y = atomicAdd(&deg[d1.y], 1);
    r1.z = atomicAdd(&deg[d1.z], 1);
    r1.w = atomicAdd(&deg[d1.w], 1);
    rank4[t * 2]     = r0;
    rank4[t * 2 + 1] = r1;
}

// ---------------- exclusive scan (3 kernels) ----------------
__global__ __launch_bounds__(256) void scan1_kernel(const int* __restrict__ deg,
                                                    int* __restrict__ offs,
                                                    int* __restrict__ bsum) {
    __shared__ int sh[256];
    int b = blockIdx.x, t = threadIdx.x;
    int base = b * SCAN_CHUNK + t * 8;
    int v[8];
    int s = 0;
#pragma unroll
    for (int j = 0; j < 8; ++j) {
        int i = base + j;
        v[j] = (i < NN) ? deg[i] : 0;
        s += v[j];
    }
    sh[t] = s;
    __syncthreads();
    for (int o = 1; o < 256; o <<= 1) {
        int add = (t >= o) ? sh[t - o] : 0;
        __syncthreads();
        sh[t] += add;
        __syncthreads();
    }
    int incl = sh[t];
    int run = incl - s;
#pragma unroll
    for (int j = 0; j < 8; ++j) {
        int i = base + j;
        if (i < NN) offs[i] = run;
        run += v[j];
    }
    if (t == 255) bsum[b] = incl;
}

__global__ void scan2_kernel(int* __restrict__ bsum, int* __restrict__ offs) {
    int t = threadIdx.x;
    int x = (t < NB_SCAN) ? bsum[t] : 0;
    int v = x;
#pragma unroll
    for (int o = 1; o < 64; o <<= 1) {
        int u = __shfl_up(v, o);
        if (t >= o) v += u;
    }
    if (t < NB_SCAN) bsum[t] = v - x;
    if (t == NB_SCAN - 1) offs[NN] = v;
}

__global__ __launch_bounds__(256) void scan3_kernel(int* __restrict__ offs,
                                                    const int* __restrict__ bsum) {
    int b = blockIdx.x;
    int add = bsum[b];
    if (add == 0) return;
    int base = b * SCAN_CHUNK + threadIdx.x * 8;
#pragma unroll
    for (int j = 0; j < 8; ++j) {
        int i = base + j;
        if (i < NN) offs[i] += add;
    }
}

// ---- CSR fill: no atomics, 8 edges/thread, independent scatters ----
__global__ __launch_bounds__(256) void fill_csr_kernel(const int4* __restrict__ src4,
                                                       const int4* __restrict__ dst4,
                                                       const int4* __restrict__ rank4,
                                                       const int* __restrict__ offs,
                                                       int* __restrict__ csr_src) {
    int t = blockIdx.x * 256 + threadIdx.x;     // group of 8 edges
    if (t >= NE / 8) return;
    int4 d0 = dst4[t * 2],     d1 = dst4[t * 2 + 1];
    int4 r0 = rank4[t * 2],    r1 = rank4[t * 2 + 1];
    int4 s0 = src4[t * 2],     s1 = src4[t * 2 + 1];
    csr_src[offs[d0.x] + r0.x] = s0.x;
    csr_src[offs[d0.y] + r0.y] = s0.y;
    csr_src[offs[d0.z] + r0.z] = s0.z;
    csr_src[offs[d0.w] + r0.w] = s0.w;
    csr_src[offs[d1.x] + r1.x] = s1.x;
    csr_src[offs[d1.y] + r1.y] = s1.y;
    csr_src[offs[d1.z] + r1.z] = s1.z;
    csr_src[offs[d1.w] + r1.w] = s1.w;
}

// ---------------- softmax + aggregation (single pass) ----------------
// one wave = 4 nodes; 16 lanes per node. lane sub owns cols (d=sub, d=16+sub)
// of all 4 heads: uint4 at featu4[s*16+sub] = {h0,h1,h2,h3}, lo16=d=sub, hi16=d=16+sub.
#define CH 32
__global__ __launch_bounds__(256) void aggregate_kernel(const uint4* __restrict__ featu4,
                                                        const float4* __restrict__ el4,
                                                        const float4* __restrict__ er4,
                                                        const int* __restrict__ offs,
                                                        const int* __restrict__ csr_src,
                                                        float* __restrict__ out) {
    __shared__ int    s_sv[4][4][CH];
    __shared__ float4 s_a4[4][4][CH];

    const int tid = threadIdx.x;
    const int lane = tid & 63, wv = tid >> 6;
    const int g = lane >> 4, sub = lane & 15;
    const int node = blockIdx.x * 16 + wv * 4 + g;   // NN == 6250*16 exactly
    const int beg = offs[node], end = offs[node + 1];

    const float4 erv = er4[node];
    float4 sm = make_float4(0.f, 0.f, 0.f, 0.f);
    float acc[8];
#pragma unroll
    for (int i = 0; i < 8; ++i) acc[i] = 0.f;

    for (int c0 = beg; c0 < end; c0 += CH) {
        int cnt = end - c0;
        if (cnt > CH) cnt = CH;
        // stage weights: lane handles slots sub and sub+16
#pragma unroll
        for (int t = 0; t < 2; ++t) {
            int slot = sub + t * 16;
            if (slot < cnt) {
                int s = csr_src[c0 + slot];
                float4 e = el4[s];
                float4 w;
                w.x = __expf(lrelu(e.x + erv.x));
                w.y = __expf(lrelu(e.y + erv.y));
                w.z = __expf(lrelu(e.z + erv.z));
                w.w = __expf(lrelu(e.w + erv.w));
                sm.x += w.x; sm.y += w.y; sm.z += w.z; sm.w += w.w;
                s_sv[wv][g][slot] = s;
                s_a4[wv][g][slot] = w;
            }
        }
        // gather: unroll 4 for MLP (4 dwordx4 loads in flight)
        int j = 0;
        for (; j + 4 <= cnt; j += 4) {
            int s0 = s_sv[wv][g][j + 0];
            int s1 = s_sv[wv][g][j + 1];
            int s2 = s_sv[wv][g][j + 2];
            int s3 = s_sv[wv][g][j + 3];
            uint4 u0 = featu4[(size_t)s0 * 16 + sub];
            uint4 u1 = featu4[(size_t)s1 * 16 + sub];
            uint4 u2 = featu4[(size_t)s2 * 16 + sub];
            uint4 u3 = featu4[(size_t)s3 * 16 + sub];
            float4 w0 = s_a4[wv][g][j + 0];
            float4 w1 = s_a4[wv][g][j + 1];
            float4 w2 = s_a4[wv][g][j + 2];
            float4 w3 = s_a4[wv][g][j + 3];
            acc[0] = fmaf(w0.x, bflo(u0.x), acc[0]); acc[1] = fmaf(w0.x, bfhi(u0.x), acc[1]);
            acc[2] = fmaf(w0.y, bflo(u0.y), acc[2]); acc[3] = fmaf(w0.y, bfhi(u0.y), acc[3]);
            acc[4] = fmaf(w0.z, bflo(u0.z), acc[4]); acc[5] = fmaf(w0.z, bfhi(u0.z), acc[5]);
            acc[6] = fmaf(w0.w, bflo(u0.w), acc[6]); acc[7] = fmaf(w0.w, bfhi(u0.w), acc[7]);
            acc[0] = fmaf(w1.x, bflo(u1.x), acc[0]); acc[1] = fmaf(w1.x, bfhi(u1.x), acc[1]);
            acc[2] = fmaf(w1.y, bflo(u1.y), acc[2]); acc[3] = fmaf(w1.y, bfhi(u1.y), acc[3]);
            acc[4] = fmaf(w1.z, bflo(u1.z), acc[4]); acc[5] = fmaf(w1.z, bfhi(u1.z), acc[5]);
            acc[6] = fmaf(w1.w, bflo(u1.w), acc[6]); acc[7] = fmaf(w1.w, bfhi(u1.w), acc[7]);
            acc[0] = fmaf(w2.x, bflo(u2.x), acc[0]); acc[1] = fmaf(w2.x, bfhi(u2.x), acc[1]);
            acc[2] = fmaf(w2.y, bflo(u2.y), acc[2]); acc[3] = fmaf(w2.y, bfhi(u2.y), acc[3]);
            acc[4] = fmaf(w2.z, bflo(u2.z), acc[4]); acc[5] = fmaf(w2.z, bfhi(u2.z), acc[5]);
            acc[6] = fmaf(w2.w, bflo(u2.w), acc[6]); acc[7] = fmaf(w2.w, bfhi(u2.w), acc[7]);
            acc[0] = fmaf(w3.x, bflo(u3.x), acc[0]); acc[1] = fmaf(w3.x, bfhi(u3.x), acc[1]);
            acc[2] = fmaf(w3.y, bflo(u3.y), acc[2]); acc[3] = fmaf(w3.y, bfhi(u3.y), acc[3]);
            acc[4] = fmaf(w3.z, bflo(u3.z), acc[4]); acc[5] = fmaf(w3.z, bfhi(u3.z), acc[5]);
            acc[6] = fmaf(w3.w, bflo(u3.w), acc[6]); acc[7] = fmaf(w3.w, bfhi(u3.w), acc[7]);
        }
        for (; j < cnt; ++j) {
            int s = s_sv[wv][g][j];
            uint4 u = featu4[(size_t)s * 16 + sub];
            float4 w = s_a4[wv][g][j];
            acc[0] = fmaf(w.x, bflo(u.x), acc[0]); acc[1] = fmaf(w.x, bfhi(u.x), acc[1]);
            acc[2] = fmaf(w.y, bflo(u.y), acc[2]); acc[3] = fmaf(w.y, bfhi(u.y), acc[3]);
            acc[4] = fmaf(w.z, bflo(u.z), acc[4]); acc[5] = fmaf(w.z, bfhi(u.z), acc[5]);
            acc[6] = fmaf(w.w, bflo(u.w), acc[6]); acc[7] = fmaf(w.w, bfhi(u.w), acc[7]);
        }
    }

    // reduce denominators across the 16 lanes of this node
#pragma unroll
    for (int o = 1; o < 16; o <<= 1) {
        sm.x += __shfl_xor(sm.x, o);
        sm.y += __shfl_xor(sm.y, o);
        sm.z += __shfl_xor(sm.z, o);
        sm.w += __shfl_xor(sm.w, o);
    }
    float ix = 1.f / fmaxf(sm.x, 1e-9f);
    float iy = 1.f / fmaxf(sm.y, 1e-9f);
    float iz = 1.f / fmaxf(sm.z, 1e-9f);
    float iw = 1.f / fmaxf(sm.w, 1e-9f);
    float ox = 0.25f * (acc[0] * ix + acc[2] * iy + acc[4] * iz + acc[6] * iw);
    float oy = 0.25f * (acc[1] * ix + acc[3] * iy + acc[5] * iz + acc[7] * iw);
    out[node * 32 + sub]      = ox;
    out[node * 32 + 16 + sub] = oy;
}

// ---------------- launch ----------------
extern "C" void kernel_launch(void* const* d_in, const int* in_sizes, int n_in,
                              void* d_out, int out_size, void* d_ws, size_t ws_size,
                              hipStream_t stream) {
    const float* x      = (const float*)d_in[0];
    const float* W      = (const float*)d_in[1];
    const float* attn_l = (const float*)d_in[2];
    const float* attn_r = (const float*)d_in[3];
    const int*   src    = (const int*)d_in[4];
    const int*   dst    = (const int*)d_in[5];
    float* out = (float*)d_out;

    char* p = (char*)d_ws;
    auto alloc = [&](size_t bytes) -> void* {
        void* r = (void*)p;
        p += (bytes + 255) & ~(size_t)255;
        return r;
    };
    unsigned short* featb = (unsigned short*)alloc((size_t)NN * HD * 2);
    unsigned int*   wswz  = (unsigned int*)alloc(4096 * 16);
    float* el     = (float*)alloc((size_t)NN * 4 * 4);
    float* er     = (float*)alloc((size_t)NN * 4 * 4);
    int*   offs   = (int*)alloc((size_t)(NN + 1) * 4);
    int*   deg    = (int*)alloc((size_t)NN * 4);
    int*   rank   = (int*)alloc((size_t)NE * 4);
    int*   bsum   = (int*)alloc(64 * 4);
    int*   csr    = (int*)alloc((size_t)NE * 4);

    hipMemsetAsync(deg, 0, (size_t)NN * 4, stream);

    prep_w_kernel<<<16, 256, 0, stream>>>(W, wswz);
    gemm_kernel<<<(NN + 63) / 64, 256, 0, stream>>>(x, (const uint4*)wswz, attn_l, attn_r,
                                                    featb, el, er);
    hist_kernel<<<(NE / 8 + 255) / 256, 256, 0, stream>>>((const int4*)dst, deg, (int4*)rank);
    scan1_kernel<<<NB_SCAN, 256, 0, stream>>>(deg, offs, bsum);
    scan2_kernel<<<1, 64, 0, stream>>>(bsum, offs);
    scan3_kernel<<<NB_SCAN, 256, 0, stream>>>(offs, bsum);
    fill_csr_kernel<<<(NE / 8 + 255) / 256, 256, 0, stream>>>((const int4*)src, (const int4*)dst,
                                                              (const int4*)rank, offs, csr);
    aggregate_kernel<<<NN / 16, 256, 0, stream>>>((const uint4*)featb, (const float4*)el,
                                                  (const float4*)er, offs, csr, out);
}

// Round 6
// 374.715 us; speedup vs baseline: 1.5882x; 1.0033x over previous
//
#include <hip/hip_runtime.h>
#include <math.h>

#define NN 100000
#define NE 1600000
#define IN_DIM 256
#define HD 128           // HEADS*OUT_DIM
#define NEG_SLOPE 0.2f
#define SCAN_CHUNK 2048
#define NB_SCAN ((NN + SCAN_CHUNK - 1) / SCAN_CHUNK)   // 49

typedef __attribute__((ext_vector_type(8))) __bf16 bf16x8;
typedef __attribute__((ext_vector_type(4))) float floatx4;

__device__ inline unsigned short f2bf(float f) {
    unsigned int b = __float_as_uint(f);
    b += 0x7fffu + ((b >> 16) & 1u);   // round-to-nearest-even
    return (unsigned short)(b >> 16);
}
__device__ inline unsigned int pk(float lo, float hi) {
    return (unsigned int)f2bf(lo) | ((unsigned int)f2bf(hi) << 16);
}
__device__ inline float bflo(unsigned int u) { return __uint_as_float(u << 16); }
__device__ inline float bfhi(unsigned int u) { return __uint_as_float(u & 0xffff0000u); }
__device__ inline float lrelu(float v) { return (v > 0.f) ? v : v * NEG_SLOPE; }

// ---- prep: swizzle W[256][128] fp32 -> bf16 B-fragments for 16x16x32 MFMA ----
// frag f = (c*8+t)*64+lane holds B[k=c*32+(lane>>4)*8+j][n=t*16+(lane&15)], j=0..7
__global__ __launch_bounds__(256) void prep_w_kernel(const float* __restrict__ W,
                                                     unsigned int* __restrict__ wswz) {
    int g = blockIdx.x * 256 + threadIdx.x;   // 0..4095
    int lane = g & 63;
    int t = (g >> 6) & 7;
    int c = g >> 9;
    int sub = lane & 15, quad = lane >> 4;
    int n = t * 16 + sub;
    int kbase = c * 32 + quad * 8;
    unsigned int ob = (unsigned int)g * 4;
#pragma unroll
    for (int i = 0; i < 4; ++i) {
        float lo = W[(size_t)(kbase + 2 * i) * HD + n];
        float hi = W[(size_t)(kbase + 2 * i + 1) * HD + n];
        wswz[ob + i] = pk(lo, hi);
    }
}

// ---- GEMM (MFMA): feat_bf16 = bf16(x @ W), el/er fused from fp32 acc ----
// Block = 256 rows: 4 waves x 4 m-tiles of 16 rows. Bs staged ONCE per block.
// feat layout: shorts [row][sub*8 + t]  (t = n-tile, sub = col-within-tile)
__global__ __launch_bounds__(256) void gemm_kernel(const float* __restrict__ x,
                                                   const uint4* __restrict__ wswz,
                                                   const float* __restrict__ attn_l,
                                                   const float* __restrict__ attn_r,
                                                   unsigned short* __restrict__ featb,
                                                   float* __restrict__ el,
                                                   float* __restrict__ er) {
    __shared__ uint4 Bs[4096];                    // 64 KB: all 64 B-fragments
    const int tid = threadIdx.x;
    for (int i = tid; i < 4096; i += 256) Bs[i] = wswz[i];

    const int lane = tid & 63, wv = tid >> 6;
    const int sub = lane & 15, quad = lane >> 4;
    const int row0 = blockIdx.x * 256 + wv * 64;  // wave covers rows row0..row0+63

    const float* xp[4];
#pragma unroll
    for (int mt = 0; mt < 4; ++mt) {
        int m = row0 + mt * 16 + sub;
        if (m >= NN) m = NN - 1;                  // clamp loads; stores guarded
        xp[mt] = x + (size_t)m * IN_DIM + quad * 8;
    }

    floatx4 acc[4][8];
#pragma unroll
    for (int mt = 0; mt < 4; ++mt)
#pragma unroll
        for (int t = 0; t < 8; ++t) acc[mt][t] = (floatx4){0.f, 0.f, 0.f, 0.f};
    __syncthreads();

#pragma unroll
    for (int c = 0; c < 8; ++c) {
        bf16x8 af[4];
#pragma unroll
        for (int mt = 0; mt < 4; ++mt) {
            float4 a0 = *(const float4*)(xp[mt] + c * 32);
            float4 a1 = *(const float4*)(xp[mt] + c * 32 + 4);
            uint4 au;
            au.x = pk(a0.x, a0.y); au.y = pk(a0.z, a0.w);
            au.z = pk(a1.x, a1.y); au.w = pk(a1.z, a1.w);
            af[mt] = __builtin_bit_cast(bf16x8, au);
        }
#pragma unroll
        for (int t = 0; t < 8; ++t) {
            bf16x8 bfr = __builtin_bit_cast(bf16x8, Bs[(c * 8 + t) * 64 + lane]);
#pragma unroll
            for (int mt = 0; mt < 4; ++mt)
                acc[mt][t] = __builtin_amdgcn_mfma_f32_16x16x32_bf16(af[mt], bfr, acc[mt][t], 0, 0, 0);
        }
    }

    // attn vectors: col = t*16+sub -> flat idx = t*16+sub
    float al[8], ar[8];
#pragma unroll
    for (int t = 0; t < 8; ++t) {
        al[t] = attn_l[t * 16 + sub];
        ar[t] = attn_r[t * 16 + sub];
    }

#pragma unroll
    for (int mt = 0; mt < 4; ++mt) {
#pragma unroll
        for (int r = 0; r < 4; ++r) {
            int row = row0 + mt * 16 + quad * 4 + r;   // C/D: row = quad*4 + reg
            uint4 fv;
            fv.x = pk(acc[mt][0][r], acc[mt][1][r]);
            fv.y = pk(acc[mt][2][r], acc[mt][3][r]);
            fv.z = pk(acc[mt][4][r], acc[mt][5][r]);
            fv.w = pk(acc[mt][6][r], acc[mt][7][r]);
            float pl[4], pr[4];
#pragma unroll
            for (int hh = 0; hh < 4; ++hh) {
                pl[hh] = acc[mt][2 * hh][r] * al[2 * hh] + acc[mt][2 * hh + 1][r] * al[2 * hh + 1];
                pr[hh] = acc[mt][2 * hh][r] * ar[2 * hh] + acc[mt][2 * hh + 1][r] * ar[2 * hh + 1];
            }
#pragma unroll
            for (int o = 1; o < 16; o <<= 1) {
#pragma unroll
                for (int hh = 0; hh < 4; ++hh) {
                    pl[hh] += __shfl_xor(pl[hh], o);
                    pr[hh] += __shfl_xor(pr[hh], o);
                }
            }
            if (row < NN) {
                *(uint4*)(featb + (size_t)row * HD + sub * 8) = fv;
                if (sub < 4) {
                    float vl = (sub == 0) ? pl[0] : (sub == 1) ? pl[1] : (sub == 2) ? pl[2] : pl[3];
                    float vr = (sub == 0) ? pr[0] : (sub == 1) ? pr[1] : (sub == 2) ? pr[2] : pr[3];
                    el[row * 4 + sub] = vl;
                    er[row * 4 + sub] = vr;
                }
            }
        }
    }
}

// ---- degree histogram + rank (8 edges/thread, coalesced rank write) ----
__global__ __launch_bounds__(256) void hist_kernel(const int4* __restrict__ dst4,
                                                   int* __restrict__ deg,
                                                   int4* __restrict__ rank4) {
    int t = blockIdx.x * 256 + threadIdx.x;     // group of 8 edges
    if (t >= NE / 8) return;
    int4 d0 = dst4[t * 2];
    int4 d1 = dst4[t * 2 + 1];
    int4 r0, r1;
    r0.x = atomicAdd(&deg[d0.x], 1);
    r0.y = atomicAdd(&deg[d0.y], 1);
    r0.z = atomicAdd(&deg[d0.z], 1);
    r0.w = atomicAdd(&deg[d0.w], 1);
    r1.x = atomicAdd(&deg[d1.x], 1);
    r1.y = atomicAdd(&deg[d1.y], 1);
    r1.z = atomicAdd(&deg[d1.z], 1);
    r1.w = atomicAdd(&deg[d1.w], 1);
    rank4[t * 2]     = r0;
    rank4[t * 2 + 1] = r1;
}

// ---------------- exclusive scan (3 kernels) ----------------
__global__ __launch_bounds__(256) void scan1_kernel(const int* __restrict__ deg,
                                                    int* __restrict__ offs,
                                                    int* __restrict__ bsum) {
    __shared__ int sh[256];
    int b = blockIdx.x, t = threadIdx.x;
    int base = b * SCAN_CHUNK + t * 8;
    int v[8];
    int s = 0;
#pragma unroll
    for (int j = 0; j < 8; ++j) {
        int i = base + j;
        v[j] = (i < NN) ? deg[i] : 0;
        s += v[j];
    }
    sh[t] = s;
    __syncthreads();
    for (int o = 1; o < 256; o <<= 1) {
        int add = (t >= o) ? sh[t - o] : 0;
        __syncthreads();
        sh[t] += add;
        __syncthreads();
    }
    int incl = sh[t];
    int run = incl - s;
#pragma unroll
    for (int j = 0; j < 8; ++j) {
        int i = base + j;
        if (i < NN) offs[i] = run;
        run += v[j];
    }
    if (t == 255) bsum[b] = incl;
}

__global__ void scan2_kernel(int* __restrict__ bsum, int* __restrict__ offs) {
    int t = threadIdx.x;
    int x = (t < NB_SCAN) ? bsum[t] : 0;
    int v = x;
#pragma unroll
    for (int o = 1; o < 64; o <<= 1) {
        int u = __shfl_up(v, o);
        if (t >= o) v += u;
    }
    if (t < NB_SCAN) bsum[t] = v - x;
    if (t == NB_SCAN - 1) offs[NN] = v;
}

__global__ __launch_bounds__(256) void scan3_kernel(int* __restrict__ offs,
                                                    const int* __restrict__ bsum) {
    int b = blockIdx.x;
    int add = bsum[b];
    if (add == 0) return;
    int base = b * SCAN_CHUNK + threadIdx.x * 8;
#pragma unroll
    for (int j = 0; j < 8; ++j) {
        int i = base + j;
        if (i < NN) offs[i] += add;
    }
}

// ---- CSR fill: no atomics, 8 edges/thread, independent scatters ----
__global__ __launch_bounds__(256) void fill_csr_kernel(const int4* __restrict__ src4,
                                                       const int4* __restrict__ dst4,
                                                       const int4* __restrict__ rank4,
                                                       const int* __restrict__ offs,
                                                       int* __restrict__ csr_src) {
    int t = blockIdx.x * 256 + threadIdx.x;     // group of 8 edges
    if (t >= NE / 8) return;
    int4 d0 = dst4[t * 2],     d1 = dst4[t * 2 + 1];
    int4 r0 = rank4[t * 2],    r1 = rank4[t * 2 + 1];
    int4 s0 = src4[t * 2],     s1 = src4[t * 2 + 1];
    csr_src[offs[d0.x] + r0.x] = s0.x;
    csr_src[offs[d0.y] + r0.y] = s0.y;
    csr_src[offs[d0.z] + r0.z] = s0.z;
    csr_src[offs[d0.w] + r0.w] = s0.w;
    csr_src[offs[d1.x] + r1.x] = s1.x;
    csr_src[offs[d1.y] + r1.y] = s1.y;
    csr_src[offs[d1.z] + r1.z] = s1.z;
    csr_src[offs[d1.w] + r1.w] = s1.w;
}

// ---------------- softmax + aggregation (single pass) ----------------
// one wave = 4 nodes; 16 lanes per node. lane sub owns cols (d=sub, d=16+sub)
// of all 4 heads: uint4 at featu4[s*16+sub] = {h0,h1,h2,h3}, lo16=d=sub, hi16=d=16+sub.
#define CH 32
__global__ __launch_bounds__(256) void aggregate_kernel(const uint4* __restrict__ featu4,
                                                        const float4* __restrict__ el4,
                                                        const float4* __restrict__ er4,
                                                        const int* __restrict__ offs,
                                                        const int* __restrict__ csr_src,
                                                        float* __restrict__ out) {
    __shared__ int    s_sv[4][4][CH];
    __shared__ float4 s_a4[4][4][CH];

    const int tid = threadIdx.x;
    const int lane = tid & 63, wv = tid >> 6;
    const int g = lane >> 4, sub = lane & 15;
    const int node = blockIdx.x * 16 + wv * 4 + g;   // NN == 6250*16 exactly
    const int beg = offs[node], end = offs[node + 1];

    const float4 erv = er4[node];
    float4 sm = make_float4(0.f, 0.f, 0.f, 0.f);
    float acc[8];
#pragma unroll
    for (int i = 0; i < 8; ++i) acc[i] = 0.f;

    for (int c0 = beg; c0 < end; c0 += CH) {
        int cnt = end - c0;
        if (cnt > CH) cnt = CH;
        // stage weights: lane handles slots sub and sub+16
#pragma unroll
        for (int t = 0; t < 2; ++t) {
            int slot = sub + t * 16;
            if (slot < cnt) {
                int s = csr_src[c0 + slot];
                float4 e = el4[s];
                float4 w;
                w.x = __expf(lrelu(e.x + erv.x));
                w.y = __expf(lrelu(e.y + erv.y));
                w.z = __expf(lrelu(e.z + erv.z));
                w.w = __expf(lrelu(e.w + erv.w));
                sm.x += w.x; sm.y += w.y; sm.z += w.z; sm.w += w.w;
                s_sv[wv][g][slot] = s;
                s_a4[wv][g][slot] = w;
            }
        }
        // gather: unroll 4 for MLP (4 dwordx4 loads in flight)
        int j = 0;
        for (; j + 4 <= cnt; j += 4) {
            int s0 = s_sv[wv][g][j + 0];
            int s1 = s_sv[wv][g][j + 1];
            int s2 = s_sv[wv][g][j + 2];
            int s3 = s_sv[wv][g][j + 3];
            uint4 u0 = featu4[(size_t)s0 * 16 + sub];
            uint4 u1 = featu4[(size_t)s1 * 16 + sub];
            uint4 u2 = featu4[(size_t)s2 * 16 + sub];
            uint4 u3 = featu4[(size_t)s3 * 16 + sub];
            float4 w0 = s_a4[wv][g][j + 0];
            float4 w1 = s_a4[wv][g][j + 1];
            float4 w2 = s_a4[wv][g][j + 2];
            float4 w3 = s_a4[wv][g][j + 3];
            acc[0] = fmaf(w0.x, bflo(u0.x), acc[0]); acc[1] = fmaf(w0.x, bfhi(u0.x), acc[1]);
            acc[2] = fmaf(w0.y, bflo(u0.y), acc[2]); acc[3] = fmaf(w0.y, bfhi(u0.y), acc[3]);
            acc[4] = fmaf(w0.z, bflo(u0.z), acc[4]); acc[5] = fmaf(w0.z, bfhi(u0.z), acc[5]);
            acc[6] = fmaf(w0.w, bflo(u0.w), acc[6]); acc[7] = fmaf(w0.w, bfhi(u0.w), acc[7]);
            acc[0] = fmaf(w1.x, bflo(u1.x), acc[0]); acc[1] = fmaf(w1.x, bfhi(u1.x), acc[1]);
            acc[2] = fmaf(w1.y, bflo(u1.y), acc[2]); acc[3] = fmaf(w1.y, bfhi(u1.y), acc[3]);
            acc[4] = fmaf(w1.z, bflo(u1.z), acc[4]); acc[5] = fmaf(w1.z, bfhi(u1.z), acc[5]);
            acc[6] = fmaf(w1.w, bflo(u1.w), acc[6]); acc[7] = fmaf(w1.w, bfhi(u1.w), acc[7]);
            acc[0] = fmaf(w2.x, bflo(u2.x), acc[0]); acc[1] = fmaf(w2.x, bfhi(u2.x), acc[1]);
            acc[2] = fmaf(w2.y, bflo(u2.y), acc[2]); acc[3] = fmaf(w2.y, bfhi(u2.y), acc[3]);
            acc[4] = fmaf(w2.z, bflo(u2.z), acc[4]); acc[5] = fmaf(w2.z, bfhi(u2.z), acc[5]);
            acc[6] = fmaf(w2.w, bflo(u2.w), acc[6]); acc[7] = fmaf(w2.w, bfhi(u2.w), acc[7]);
            acc[0] = fmaf(w3.x, bflo(u3.x), acc[0]); acc[1] = fmaf(w3.x, bfhi(u3.x), acc[1]);
            acc[2] = fmaf(w3.y, bflo(u3.y), acc[2]); acc[3] = fmaf(w3.y, bfhi(u3.y), acc[3]);
            acc[4] = fmaf(w3.z, bflo(u3.z), acc[4]); acc[5] = fmaf(w3.z, bfhi(u3.z), acc[5]);
            acc[6] = fmaf(w3.w, bflo(u3.w), acc[6]); acc[7] = fmaf(w3.w, bfhi(u3.w), acc[7]);
        }
        for (; j < cnt; ++j) {
            int s = s_sv[wv][g][j];
            uint4 u = featu4[(size_t)s * 16 + sub];
            float4 w = s_a4[wv][g][j];
            acc[0] = fmaf(w.x, bflo(u.x), acc[0]); acc[1] = fmaf(w.x, bfhi(u.x), acc[1]);
            acc[2] = fmaf(w.y, bflo(u.y), acc[2]); acc[3] = fmaf(w.y, bfhi(u.y), acc[3]);
            acc[4] = fmaf(w.z, bflo(u.z), acc[4]); acc[5] = fmaf(w.z, bfhi(u.z), acc[5]);
            acc[6] = fmaf(w.w, bflo(u.w), acc[6]); acc[7] = fmaf(w.w, bfhi(u.w), acc[7]);
        }
    }

    // reduce denominators across the 16 lanes of this node
#pragma unroll
    for (int o = 1; o < 16; o <<= 1) {
        sm.x += __shfl_xor(sm.x, o);
        sm.y += __shfl_xor(sm.y, o);
        sm.z += __shfl_xor(sm.z, o);
        sm.w += __shfl_xor(sm.w, o);
    }
    float ix = 1.f / fmaxf(sm.x, 1e-9f);
    float iy = 1.f / fmaxf(sm.y, 1e-9f);
    float iz = 1.f / fmaxf(sm.z, 1e-9f);
    float iw = 1.f / fmaxf(sm.w, 1e-9f);
    float ox = 0.25f * (acc[0] * ix + acc[2] * iy + acc[4] * iz + acc[6] * iw);
    float oy = 0.25f * (acc[1] * ix + acc[3] * iy + acc[5] * iz + acc[7] * iw);
    out[node * 32 + sub]      = ox;
    out[node * 32 + 16 + sub] = oy;
}

// ---------------- launch ----------------
extern "C" void kernel_launch(void* const* d_in, const int* in_sizes, int n_in,
                              void* d_out, int out_size, void* d_ws, size_t ws_size,
                              hipStream_t stream) {
    const float* x      = (const float*)d_in[0];
    const float* W      = (const float*)d_in[1];
    const float* attn_l = (const float*)d_in[2];
    const float* attn_r = (const float*)d_in[3];
    const int*   src    = (const int*)d_in[4];
    const int*   dst    = (const int*)d_in[5];
    float* out = (float*)d_out;

    char* p = (char*)d_ws;
    auto alloc = [&](size_t bytes) -> void* {
        void* r = (void*)p;
        p += (bytes + 255) & ~(size_t)255;
        return r;
    };
    unsigned short* featb = (unsigned short*)alloc((size_t)NN * HD * 2);
    unsigned int*   wswz  = (unsigned int*)alloc(4096 * 16);
    float* el     = (float*)alloc((size_t)NN * 4 * 4);
    float* er     = (float*)alloc((size_t)NN * 4 * 4);
    int*   offs   = (int*)alloc((size_t)(NN + 1) * 4);
    int*   deg    = (int*)alloc((size_t)NN * 4);
    int*   rank   = (int*)alloc((size_t)NE * 4);
    int*   bsum   = (int*)alloc(64 * 4);
    int*   csr    = (int*)alloc((size_t)NE * 4);

    hipMemsetAsync(deg, 0, (size_t)NN * 4, stream);

    prep_w_kernel<<<16, 256, 0, stream>>>(W, wswz);
    gemm_kernel<<<(NN + 255) / 256, 256, 0, stream>>>(x, (const uint4*)wswz, attn_l, attn_r,
                                                      featb, el, er);
    hist_kernel<<<(NE / 8 + 255) / 256, 256, 0, stream>>>((const int4*)dst, deg, (int4*)rank);
    scan1_kernel<<<NB_SCAN, 256, 0, stream>>>(deg, offs, bsum);
    scan2_kernel<<<1, 64, 0, stream>>>(bsum, offs);
    scan3_kernel<<<NB_SCAN, 256, 0, stream>>>(offs, bsum);
    fill_csr_kernel<<<(NE / 8 + 255) / 256, 256, 0, stream>>>((const int4*)src, (const int4*)dst,
                                                              (const int4*)rank, offs, csr);
    aggregate_kernel<<<NN / 16, 256, 0, stream>>>((const uint4*)featb, (const float4*)el,
                                                  (const float4*)er, offs, csr, out);
}

// Round 7
// 373.605 us; speedup vs baseline: 1.5929x; 1.0030x over previous
//
#include <hip/hip_runtime.h>
#include <math.h>

#define NN 100000
#define NE 1600000
#define IN_DIM 256
#define HD 128           // HEADS*OUT_DIM
#define NEG_SLOPE 0.2f
#define SCAN_CHUNK 2048
#define NB_SCAN ((NN + SCAN_CHUNK - 1) / SCAN_CHUNK)   // 49

typedef __attribute__((ext_vector_type(8))) __bf16 bf16x8;
typedef __attribute__((ext_vector_type(4))) float floatx4;

__device__ inline unsigned short f2bf(float f) {
    unsigned int b = __float_as_uint(f);
    b += 0x7fffu + ((b >> 16) & 1u);   // round-to-nearest-even
    return (unsigned short)(b >> 16);
}
__device__ inline unsigned int pk(float lo, float hi) {
    return (unsigned int)f2bf(lo) | ((unsigned int)f2bf(hi) << 16);
}
__device__ inline float bflo(unsigned int u) { return __uint_as_float(u << 16); }
__device__ inline float bfhi(unsigned int u) { return __uint_as_float(u & 0xffff0000u); }
__device__ inline float lrelu(float v) { return (v > 0.f) ? v : v * NEG_SLOPE; }

// ---- prep: swizzle W[256][128] fp32 -> bf16 B-fragments for 16x16x32 MFMA ----
// frag f = (c*8+t)*64+lane holds B[k=c*32+(lane>>4)*8+j][n=t*16+(lane&15)], j=0..7
__global__ __launch_bounds__(256) void prep_w_kernel(const float* __restrict__ W,
                                                     unsigned int* __restrict__ wswz) {
    int g = blockIdx.x * 256 + threadIdx.x;   // 0..4095
    int lane = g & 63;
    int t = (g >> 6) & 7;
    int c = g >> 9;
    int sub = lane & 15, quad = lane >> 4;
    int n = t * 16 + sub;
    int kbase = c * 32 + quad * 8;
    unsigned int ob = (unsigned int)g * 4;
#pragma unroll
    for (int i = 0; i < 4; ++i) {
        float lo = W[(size_t)(kbase + 2 * i) * HD + n];
        float hi = W[(size_t)(kbase + 2 * i + 1) * HD + n];
        wswz[ob + i] = pk(lo, hi);
    }
}

// ---- GEMM (MFMA, NO LDS): feat_bf16 = bf16(x @ W), el/er fused ----
// One wave = 32 rows (2 m-tiles x 16). B-fragments read directly from L2
// (wswz is 64 KB, resident in every XCD L2). No barriers, no LDS -> high
// occupancy; 12 independent loads in flight per K-chunk per wave.
// feat layout: shorts [row][sub*8 + t]  (t = n-tile, sub = col-within-tile)
__global__ __launch_bounds__(256) void gemm_kernel(const float* __restrict__ x,
                                                   const uint4* __restrict__ wswz,
                                                   const float* __restrict__ attn_l,
                                                   const float* __restrict__ attn_r,
                                                   unsigned short* __restrict__ featb,
                                                   float* __restrict__ el,
                                                   float* __restrict__ er) {
    const int tid = threadIdx.x;
    const int lane = tid & 63, wv = tid >> 6;
    const int sub = lane & 15, quad = lane >> 4;
    const int row0 = blockIdx.x * 128 + wv * 32;  // wave covers rows row0..row0+31

    const float* xp[2];
#pragma unroll
    for (int mt = 0; mt < 2; ++mt) {
        int m = row0 + mt * 16 + sub;
        if (m >= NN) m = NN - 1;                  // clamp loads; stores guarded
        xp[mt] = x + (size_t)m * IN_DIM + quad * 8;
    }

    floatx4 acc[2][8];
#pragma unroll
    for (int mt = 0; mt < 2; ++mt)
#pragma unroll
        for (int t = 0; t < 8; ++t) acc[mt][t] = (floatx4){0.f, 0.f, 0.f, 0.f};

#pragma unroll
    for (int c = 0; c < 8; ++c) {
        uint4 bu[8];
#pragma unroll
        for (int t = 0; t < 8; ++t) bu[t] = wswz[(c * 8 + t) * 64 + lane];
        bf16x8 af[2];
#pragma unroll
        for (int mt = 0; mt < 2; ++mt) {
            float4 a0 = *(const float4*)(xp[mt] + c * 32);
            float4 a1 = *(const float4*)(xp[mt] + c * 32 + 4);
            uint4 au;
            au.x = pk(a0.x, a0.y); au.y = pk(a0.z, a0.w);
            au.z = pk(a1.x, a1.y); au.w = pk(a1.z, a1.w);
            af[mt] = __builtin_bit_cast(bf16x8, au);
        }
#pragma unroll
        for (int t = 0; t < 8; ++t) {
            bf16x8 bfr = __builtin_bit_cast(bf16x8, bu[t]);
#pragma unroll
            for (int mt = 0; mt < 2; ++mt)
                acc[mt][t] = __builtin_amdgcn_mfma_f32_16x16x32_bf16(af[mt], bfr, acc[mt][t], 0, 0, 0);
        }
    }

    // attn vectors: col = t*16+sub -> flat idx = t*16+sub
    float al[8], ar[8];
#pragma unroll
    for (int t = 0; t < 8; ++t) {
        al[t] = attn_l[t * 16 + sub];
        ar[t] = attn_r[t * 16 + sub];
    }

#pragma unroll
    for (int mt = 0; mt < 2; ++mt) {
#pragma unroll
        for (int r = 0; r < 4; ++r) {
            int row = row0 + mt * 16 + quad * 4 + r;   // C/D: row = quad*4 + reg
            uint4 fv;
            fv.x = pk(acc[mt][0][r], acc[mt][1][r]);
            fv.y = pk(acc[mt][2][r], acc[mt][3][r]);
            fv.z = pk(acc[mt][4][r], acc[mt][5][r]);
            fv.w = pk(acc[mt][6][r], acc[mt][7][r]);
            float pl[4], pr[4];
#pragma unroll
            for (int hh = 0; hh < 4; ++hh) {
                pl[hh] = acc[mt][2 * hh][r] * al[2 * hh] + acc[mt][2 * hh + 1][r] * al[2 * hh + 1];
                pr[hh] = acc[mt][2 * hh][r] * ar[2 * hh] + acc[mt][2 * hh + 1][r] * ar[2 * hh + 1];
            }
#pragma unroll
            for (int o = 1; o < 16; o <<= 1) {
#pragma unroll
                for (int hh = 0; hh < 4; ++hh) {
                    pl[hh] += __shfl_xor(pl[hh], o);
                    pr[hh] += __shfl_xor(pr[hh], o);
                }
            }
            if (row < NN) {
                *(uint4*)(featb + (size_t)row * HD + sub * 8) = fv;
                if (sub < 4) {
                    float vl = (sub == 0) ? pl[0] : (sub == 1) ? pl[1] : (sub == 2) ? pl[2] : pl[3];
                    float vr = (sub == 0) ? pr[0] : (sub == 1) ? pr[1] : (sub == 2) ? pr[2] : pr[3];
                    el[row * 4 + sub] = vl;
                    er[row * 4 + sub] = vr;
                }
            }
        }
    }
}

// ---- degree histogram + rank (8 edges/thread, coalesced rank write) ----
__global__ __launch_bounds__(256) void hist_kernel(const int4* __restrict__ dst4,
                                                   int* __restrict__ deg,
                                                   int4* __restrict__ rank4) {
    int t = blockIdx.x * 256 + threadIdx.x;     // group of 8 edges
    if (t >= NE / 8) return;
    int4 d0 = dst4[t * 2];
    int4 d1 = dst4[t * 2 + 1];
    int4 r0, r1;
    r0.x = atomicAdd(&deg[d0.x], 1);
    r0.y = atomicAdd(&deg[d0.y], 1);
    r0.z = atomicAdd(&deg[d0.z], 1);
    r0.w = atomicAdd(&deg[d0.w], 1);
    r1.x = atomicAdd(&deg[d1.x], 1);
    r1.y = atomicAdd(&deg[d1.y], 1);
    r1.z = atomicAdd(&deg[d1.z], 1);
    r1.w = atomicAdd(&deg[d1.w], 1);
    rank4[t * 2]     = r0;
    rank4[t * 2 + 1] = r1;
}

// ---------------- exclusive scan (3 kernels) ----------------
__global__ __launch_bounds__(256) void scan1_kernel(const int* __restrict__ deg,
                                                    int* __restrict__ offs,
                                                    int* __restrict__ bsum) {
    __shared__ int sh[256];
    int b = blockIdx.x, t = threadIdx.x;
    int base = b * SCAN_CHUNK + t * 8;
    int v[8];
    int s = 0;
#pragma unroll
    for (int j = 0; j < 8; ++j) {
        int i = base + j;
        v[j] = (i < NN) ? deg[i] : 0;
        s += v[j];
    }
    sh[t] = s;
    __syncthreads();
    for (int o = 1; o < 256; o <<= 1) {
        int add = (t >= o) ? sh[t - o] : 0;
        __syncthreads();
        sh[t] += add;
        __syncthreads();
    }
    int incl = sh[t];
    int run = incl - s;
#pragma unroll
    for (int j = 0; j < 8; ++j) {
        int i = base + j;
        if (i < NN) offs[i] = run;
        run += v[j];
    }
    if (t == 255) bsum[b] = incl;
}

__global__ void scan2_kernel(int* __restrict__ bsum, int* __restrict__ offs) {
    int t = threadIdx.x;
    int x = (t < NB_SCAN) ? bsum[t] : 0;
    int v = x;
#pragma unroll
    for (int o = 1; o < 64; o <<= 1) {
        int u = __shfl_up(v, o);
        if (t >= o) v += u;
    }
    if (t < NB_SCAN) bsum[t] = v - x;
    if (t == NB_SCAN - 1) offs[NN] = v;
}

__global__ __launch_bounds__(256) void scan3_kernel(int* __restrict__ offs,
                                                    const int* __restrict__ bsum) {
    int b = blockIdx.x;
    int add = bsum[b];
    if (add == 0) return;
    int base = b * SCAN_CHUNK + threadIdx.x * 8;
#pragma unroll
    for (int j = 0; j < 8; ++j) {
        int i = base + j;
        if (i < NN) offs[i] += add;
    }
}

// ---- CSR fill: no atomics, 8 edges/thread, independent scatters ----
__global__ __launch_bounds__(256) void fill_csr_kernel(const int4* __restrict__ src4,
                                                       const int4* __restrict__ dst4,
                                                       const int4* __restrict__ rank4,
                                                       const int* __restrict__ offs,
                                                       int* __restrict__ csr_src) {
    int t = blockIdx.x * 256 + threadIdx.x;     // group of 8 edges
    if (t >= NE / 8) return;
    int4 d0 = dst4[t * 2],     d1 = dst4[t * 2 + 1];
    int4 r0 = rank4[t * 2],    r1 = rank4[t * 2 + 1];
    int4 s0 = src4[t * 2],     s1 = src4[t * 2 + 1];
    csr_src[offs[d0.x] + r0.x] = s0.x;
    csr_src[offs[d0.y] + r0.y] = s0.y;
    csr_src[offs[d0.z] + r0.z] = s0.z;
    csr_src[offs[d0.w] + r0.w] = s0.w;
    csr_src[offs[d1.x] + r1.x] = s1.x;
    csr_src[offs[d1.y] + r1.y] = s1.y;
    csr_src[offs[d1.z] + r1.z] = s1.z;
    csr_src[offs[d1.w] + r1.w] = s1.w;
}

// ---------------- softmax + aggregation (single pass) ----------------
// one wave = 4 nodes; 16 lanes per node. lane sub owns cols (d=sub, d=16+sub)
// of all 4 heads: uint4 at featu4[s*16+sub] = {h0,h1,h2,h3}, lo16=d=sub, hi16=d=16+sub.
#define CH 32
__global__ __launch_bounds__(256) void aggregate_kernel(const uint4* __restrict__ featu4,
                                                        const float4* __restrict__ el4,
                                                        const float4* __restrict__ er4,
                                                        const int* __restrict__ offs,
                                                        const int* __restrict__ csr_src,
                                                        float* __restrict__ out) {
    __shared__ int    s_sv[4][4][CH];
    __shared__ float4 s_a4[4][4][CH];

    const int tid = threadIdx.x;
    const int lane = tid & 63, wv = tid >> 6;
    const int g = lane >> 4, sub = lane & 15;
    const int node = blockIdx.x * 16 + wv * 4 + g;   // NN == 6250*16 exactly
    const int beg = offs[node], end = offs[node + 1];

    const float4 erv = er4[node];
    float4 sm = make_float4(0.f, 0.f, 0.f, 0.f);
    float acc[8];
#pragma unroll
    for (int i = 0; i < 8; ++i) acc[i] = 0.f;

    for (int c0 = beg; c0 < end; c0 += CH) {
        int cnt = end - c0;
        if (cnt > CH) cnt = CH;
        // stage weights: lane handles slots sub and sub+16
#pragma unroll
        for (int t = 0; t < 2; ++t) {
            int slot = sub + t * 16;
            if (slot < cnt) {
                int s = csr_src[c0 + slot];
                float4 e = el4[s];
                float4 w;
                w.x = __expf(lrelu(e.x + erv.x));
                w.y = __expf(lrelu(e.y + erv.y));
                w.z = __expf(lrelu(e.z + erv.z));
                w.w = __expf(lrelu(e.w + erv.w));
                sm.x += w.x; sm.y += w.y; sm.z += w.z; sm.w += w.w;
                s_sv[wv][g][slot] = s;
                s_a4[wv][g][slot] = w;
            }
        }
        // gather: unroll 4 for MLP (4 dwordx4 loads in flight)
        int j = 0;
        for (; j + 4 <= cnt; j += 4) {
            int s0 = s_sv[wv][g][j + 0];
            int s1 = s_sv[wv][g][j + 1];
            int s2 = s_sv[wv][g][j + 2];
            int s3 = s_sv[wv][g][j + 3];
            uint4 u0 = featu4[(size_t)s0 * 16 + sub];
            uint4 u1 = featu4[(size_t)s1 * 16 + sub];
            uint4 u2 = featu4[(size_t)s2 * 16 + sub];
            uint4 u3 = featu4[(size_t)s3 * 16 + sub];
            float4 w0 = s_a4[wv][g][j + 0];
            float4 w1 = s_a4[wv][g][j + 1];
            float4 w2 = s_a4[wv][g][j + 2];
            float4 w3 = s_a4[wv][g][j + 3];
            acc[0] = fmaf(w0.x, bflo(u0.x), acc[0]); acc[1] = fmaf(w0.x, bfhi(u0.x), acc[1]);
            acc[2] = fmaf(w0.y, bflo(u0.y), acc[2]); acc[3] = fmaf(w0.y, bfhi(u0.y), acc[3]);
            acc[4] = fmaf(w0.z, bflo(u0.z), acc[4]); acc[5] = fmaf(w0.z, bfhi(u0.z), acc[5]);
            acc[6] = fmaf(w0.w, bflo(u0.w), acc[6]); acc[7] = fmaf(w0.w, bfhi(u0.w), acc[7]);
            acc[0] = fmaf(w1.x, bflo(u1.x), acc[0]); acc[1] = fmaf(w1.x, bfhi(u1.x), acc[1]);
            acc[2] = fmaf(w1.y, bflo(u1.y), acc[2]); acc[3] = fmaf(w1.y, bfhi(u1.y), acc[3]);
            acc[4] = fmaf(w1.z, bflo(u1.z), acc[4]); acc[5] = fmaf(w1.z, bfhi(u1.z), acc[5]);
            acc[6] = fmaf(w1.w, bflo(u1.w), acc[6]); acc[7] = fmaf(w1.w, bfhi(u1.w), acc[7]);
            acc[0] = fmaf(w2.x, bflo(u2.x), acc[0]); acc[1] = fmaf(w2.x, bfhi(u2.x), acc[1]);
            acc[2] = fmaf(w2.y, bflo(u2.y), acc[2]); acc[3] = fmaf(w2.y, bfhi(u2.y), acc[3]);
            acc[4] = fmaf(w2.z, bflo(u2.z), acc[4]); acc[5] = fmaf(w2.z, bfhi(u2.z), acc[5]);
            acc[6] = fmaf(w2.w, bflo(u2.w), acc[6]); acc[7] = fmaf(w2.w, bfhi(u2.w), acc[7]);
            acc[0] = fmaf(w3.x, bflo(u3.x), acc[0]); acc[1] = fmaf(w3.x, bfhi(u3.x), acc[1]);
            acc[2] = fmaf(w3.y, bflo(u3.y), acc[2]); acc[3] = fmaf(w3.y, bfhi(u3.y), acc[3]);
            acc[4] = fmaf(w3.z, bflo(u3.z), acc[4]); acc[5] = fmaf(w3.z, bfhi(u3.z), acc[5]);
            acc[6] = fmaf(w3.w, bflo(u3.w), acc[6]); acc[7] = fmaf(w3.w, bfhi(u3.w), acc[7]);
        }
        for (; j < cnt; ++j) {
            int s = s_sv[wv][g][j];
            uint4 u = featu4[(size_t)s * 16 + sub];
            float4 w = s_a4[wv][g][j];
            acc[0] = fmaf(w.x, bflo(u.x), acc[0]); acc[1] = fmaf(w.x, bfhi(u.x), acc[1]);
            acc[2] = fmaf(w.y, bflo(u.y), acc[2]); acc[3] = fmaf(w.y, bfhi(u.y), acc[3]);
            acc[4] = fmaf(w.z, bflo(u.z), acc[4]); acc[5] = fmaf(w.z, bfhi(u.z), acc[5]);
            acc[6] = fmaf(w.w, bflo(u.w), acc[6]); acc[7] = fmaf(w.w, bfhi(u.w), acc[7]);
        }
    }

    // reduce denominators across the 16 lanes of this node
#pragma unroll
    for (int o = 1; o < 16; o <<= 1) {
        sm.x += __shfl_xor(sm.x, o);
        sm.y += __shfl_xor(sm.y, o);
        sm.z += __shfl_xor(sm.z, o);
        sm.w += __shfl_xor(sm.w, o);
    }
    float ix = 1.f / fmaxf(sm.x, 1e-9f);
    float iy = 1.f / fmaxf(sm.y, 1e-9f);
    float iz = 1.f / fmaxf(sm.z, 1e-9f);
    float iw = 1.f / fmaxf(sm.w, 1e-9f);
    float ox = 0.25f * (acc[0] * ix + acc[2] * iy + acc[4] * iz + acc[6] * iw);
    float oy = 0.25f * (acc[1] * ix + acc[3] * iy + acc[5] * iz + acc[7] * iw);
    out[node * 32 + sub]      = ox;
    out[node * 32 + 16 + sub] = oy;
}

// ---------------- launch ----------------
extern "C" void kernel_launch(void* const* d_in, const int* in_sizes, int n_in,
                              void* d_out, int out_size, void* d_ws, size_t ws_size,
                              hipStream_t stream) {
    const float* x      = (const float*)d_in[0];
    const float* W      = (const float*)d_in[1];
    const float* attn_l = (const float*)d_in[2];
    const float* attn_r = (const float*)d_in[3];
    const int*   src    = (const int*)d_in[4];
    const int*   dst    = (const int*)d_in[5];
    float* out = (float*)d_out;

    char* p = (char*)d_ws;
    auto alloc = [&](size_t bytes) -> void* {
        void* r = (void*)p;
        p += (bytes + 255) & ~(size_t)255;
        return r;
    };
    unsigned short* featb = (unsigned short*)alloc((size_t)NN * HD * 2);
    unsigned int*   wswz  = (unsigned int*)alloc(4096 * 16);
    float* el     = (float*)alloc((size_t)NN * 4 * 4);
    float* er     = (float*)alloc((size_t)NN * 4 * 4);
    int*   offs   = (int*)alloc((size_t)(NN + 1) * 4);
    int*   deg    = (int*)alloc((size_t)NN * 4);
    int*   rank   = (int*)alloc((size_t)NE * 4);
    int*   bsum   = (int*)alloc(64 * 4);
    int*   csr    = (int*)alloc((size_t)NE * 4);

    hipMemsetAsync(deg, 0, (size_t)NN * 4, stream);

    prep_w_kernel<<<16, 256, 0, stream>>>(W, wswz);
    gemm_kernel<<<(NN + 127) / 128, 256, 0, stream>>>(x, (const uint4*)wswz, attn_l, attn_r,
                                                      featb, el, er);
    hist_kernel<<<(NE / 8 + 255) / 256, 256, 0, stream>>>((const int4*)dst, deg, (int4*)rank);
    scan1_kernel<<<NB_SCAN, 256, 0, stream>>>(deg, offs, bsum);
    scan2_kernel<<<1, 64, 0, stream>>>(bsum, offs);
    scan3_kernel<<<NB_SCAN, 256, 0, stream>>>(offs, bsum);
    fill_csr_kernel<<<(NE / 8 + 255) / 256, 256, 0, stream>>>((const int4*)src, (const int4*)dst,
                                                              (const int4*)rank, offs, csr);
    aggregate_kernel<<<NN / 16, 256, 0, stream>>>((const uint4*)featb, (const float4*)el,
                                                  (const float4*)er, offs, csr, out);
}